// Round 12
// baseline (103.895 us; speedup 1.0000x reference)
//
#include <hip/hip_runtime.h>
#include <hip/hip_bf16.h>

// Problem constants
constexpr int B_ = 4;
constexpr int C_ = 192;
constexpr int L_ = 4096;     // H*W
constexpr int DI = 384;      // d_inner
constexpr int DSs = 16;      // d_state
constexpr int DTR = 12;      // dt_rank
constexpr int NDBL = 44;     // dt_rank + 2*d_state
constexpr int NCHUNK = 128;  // scan chunks
constexpr int CSZ = 32;      // chunk size (== convx tile rows)
constexpr int NSUP = 8;      // super-chunks (16 chunks each)

constexpr size_t BL = (size_t)B_ * L_;  // 16384

// Workspace offsets in FLOAT units (bf16 buffers counted at half)
constexpr size_t F_SEQN = 0;                                   // bf16 BL*C
constexpr size_t F_XIN  = F_SEQN + BL * C_ / 2;                // bf16 BL*DI
constexpr size_t F_Z    = F_XIN + BL * DI / 2;                 // bf16 BL*DI
constexpr size_t F_XSB  = F_Z + BL * DI / 2;                   // bf16 BL*DI
constexpr size_t F_DBL  = F_XSB + BL * DI / 2;                 // f32  BL*NDBL
constexpr size_t F_DT   = F_DBL + BL * NDBL;                   // bf16 BL*DI
constexpr size_t F_SBUF = F_DT + BL * DI / 2;                  // f32  B*NCHUNK*DI
constexpr size_t F_HLOC = F_SBUF + (size_t)B_ * NCHUNK * DI;   // bf16 B*NCHUNK*16*DI
constexpr size_t F_SPRE = F_HLOC + (size_t)B_ * NCHUNK * DI * 16 / 2;  // f32 B*NCHUNK*DI
constexpr size_t F_HSUP = F_SPRE + (size_t)B_ * NCHUNK * DI;   // f32 B*NSUP*16*DI
constexpr size_t F_SSUP = F_HSUP + (size_t)B_ * NSUP * 16 * DI;// f32 B*NSUP*DI
constexpr size_t F_ISUP = F_SSUP + (size_t)B_ * NSUP * DI;     // f32 (unused this round)
constexpr size_t F_WBUF = F_ISUP + (size_t)B_ * NSUP * 16 * DI;// bf16 weights
// total ~= 70 MB (prior rounds used 129 MB: safe)

typedef __attribute__((ext_vector_type(8))) short bf16x8;
typedef __attribute__((ext_vector_type(4))) float f32x4;

__device__ __forceinline__ unsigned short f2bf(float v) {
  unsigned x = __builtin_bit_cast(unsigned, v);
  unsigned r = x + 0x7FFFu + ((x >> 16) & 1u);   // RNE
  return (unsigned short)(r >> 16);
}
__device__ __forceinline__ float bf2f(unsigned short u) {
  return __builtin_bit_cast(float, (unsigned)u << 16);
}
__device__ __forceinline__ void gload16(const void* g, void* l) {
  __builtin_amdgcn_global_load_lds((const __attribute__((address_space(1))) void*)g,
                                   (__attribute__((address_space(3))) void*)l, 16, 0, 0);
}
#define MFMA16(a, b, c) __builtin_amdgcn_mfma_f32_16x16x32_bf16(a, b, c, 0, 0, 0)

// ---------------- LayerNorm (blocks 0..1023, 16-row tiles) + weight cvt tail ---------
__global__ __launch_bounds__(256) void k_ln(const float* __restrict__ x,
                                            const float* __restrict__ nw,
                                            const float* __restrict__ nb,
                                            unsigned short* __restrict__ seqn,
                                            const float* __restrict__ ipw,
                                            const float* __restrict__ xpw,
                                            const float* __restrict__ opw,
                                            unsigned short* __restrict__ wbuf) {
  if (blockIdx.x >= 1024) {
    int t = (blockIdx.x - 1024) * 256 + threadIdx.x;
    if (t < 239616) {
      float v;
      if (t < 147456) v = ipw[t];
      else if (t < 165888) {
        int j = t - 147456;
        int r = j / 384, c = j - r * 384;
        v = (r < 44) ? xpw[r * 384 + c] : 0.f;
      } else v = opw[t - 165888];
      wbuf[t] = f2bf(v);
    }
    return;
  }
  __shared__ unsigned short xt[192][18];
  __shared__ float ps[16][16], ps2[16][16];
  __shared__ float mu_[16], rs_[16];
  __shared__ float wsh[192], bsh[192];
  int tid = threadIdx.x;
  int blk = blockIdx.x;          // 0..1023
  int b = blk >> 8;
  int l0 = (blk & 255) << 4;
  const float* xb = x + (size_t)b * C_ * L_;
  for (int idx = tid; idx < 192 * 4; idx += 256) {
    int c = idx >> 2, lq = idx & 3;
    float4 v = *(const float4*)&xb[(size_t)c * L_ + l0 + (lq << 2)];
    ushort2 u0, u1;
    u0.x = f2bf(v.x); u0.y = f2bf(v.y);
    u1.x = f2bf(v.z); u1.y = f2bf(v.w);
    *(ushort2*)&xt[c][(lq << 2)] = u0;
    *(ushort2*)&xt[c][(lq << 2) + 2] = u1;
  }
  if (tid < 192) { wsh[tid] = nw[tid]; bsh[tid] = nb[tid]; }
  __syncthreads();
  int ll = tid & 15, q = tid >> 4;   // 16 groups x 12 channels
  float s = 0.f, ss = 0.f;
  for (int c = q * 12; c < q * 12 + 12; ++c) {
    float v = bf2f(xt[c][ll]);
    s += v; ss += v * v;
  }
  ps[q][ll] = s; ps2[q][ll] = ss;
  __syncthreads();
  if (q == 0) {
    float st = 0.f, sst = 0.f;
#pragma unroll
    for (int g = 0; g < 16; ++g) { st += ps[g][ll]; sst += ps2[g][ll]; }
    float mu = st * (1.f / 192.f);
    float var = sst * (1.f / 192.f) - mu * mu;
    mu_[ll] = mu; rs_[ll] = rsqrtf(var + 1e-5f);
  }
  __syncthreads();
  unsigned short* so = seqn + ((size_t)b * L_ + l0) * C_;
  for (int idx = tid; idx < 16 * 192; idx += 256) {
    int l = idx / 192, c = idx - l * 192;
    so[idx] = f2bf((bf2f(xt[c][l]) - mu_[l]) * rs_[l] * wsh[c] + bsh[c]);
  }
}

// ---------------- in_proj MFMA: seqn(BL,192)bf16 @ W(768,192)^T -> xin,z bf16 --------
__global__ __launch_bounds__(256) void k_inproj(const unsigned short* __restrict__ A,
                                                const unsigned short* __restrict__ W,
                                                unsigned short* __restrict__ xin,
                                                unsigned short* __restrict__ z) {
  __shared__ unsigned short smem[16384];
  unsigned short* As = smem;
  unsigned short* Bs = smem + 8192;
  int tid = threadIdx.x;
  int w = tid >> 6, l = tid & 63;
  int wr = w >> 1, wc = w & 1;
  int m0 = blockIdx.x << 7;
  int n0 = blockIdx.y << 7;
  f32x4 acc[4][4];
#pragma unroll
  for (int i = 0; i < 4; ++i)
#pragma unroll
    for (int j = 0; j < 4; ++j) acc[i][j] = (f32x4){0.f, 0.f, 0.f, 0.f};
  int lr = l & 15, lk = l >> 4;
  for (int kt = 0; kt < 3; ++kt) {
    int k0 = kt * 64;
    if (kt) __syncthreads();
#pragma unroll
    for (int i = 0; i < 4; ++i) {
      int row = (i << 5) + (tid >> 3);
      int gc = k0 + (((tid & 7) ^ (row & 7)) << 3);
      gload16(A + (size_t)(m0 + row) * 192 + gc, &As[(i << 11) + (w << 9)]);
      gload16(W + (size_t)(n0 + row) * 192 + gc, &Bs[(i << 11) + (w << 9)]);
    }
    __syncthreads();
#pragma unroll
    for (int ks = 0; ks < 2; ++ks) {
      int s = (ks << 2) + lk;
      bf16x8 af[4], bfr[4];
#pragma unroll
      for (int mi = 0; mi < 4; ++mi) {
        int r = (wr << 6) + (mi << 4) + lr;
        af[mi] = *(const bf16x8*)&As[r * 64 + ((s ^ (r & 7)) << 3)];
      }
#pragma unroll
      for (int ni = 0; ni < 4; ++ni) {
        int r = (wc << 6) + (ni << 4) + lr;
        bfr[ni] = *(const bf16x8*)&Bs[r * 64 + ((s ^ (r & 7)) << 3)];
      }
#pragma unroll
      for (int mi = 0; mi < 4; ++mi)
#pragma unroll
        for (int ni = 0; ni < 4; ++ni) acc[mi][ni] = MFMA16(af[mi], bfr[ni], acc[mi][ni]);
    }
  }
  __syncthreads();
#pragma unroll
  for (int mi = 0; mi < 4; ++mi)
#pragma unroll
    for (int ni = 0; ni < 4; ++ni) {
      int col = (wc << 6) + (ni << 4) + lr;
#pragma unroll
      for (int r = 0; r < 4; ++r) {
        int row = (wr << 6) + (mi << 4) + (lk << 2) + r;
        smem[(row << 7) + col] = f2bf(acc[mi][ni][r]);
      }
    }
  __syncthreads();
#pragma unroll
  for (int i = 0; i < 8; ++i) {
    int chunk = i * 256 + tid;
    int row = chunk >> 4, cq = chunk & 15;
    int n = n0 + (cq << 3);
    unsigned short* dst = (n < 384) ? (xin + (size_t)(m0 + row) * DI + n)
                                    : (z + (size_t)(m0 + row) * DI + (n - 384));
    *(bf16x8*)dst = *(const bf16x8*)&smem[(row << 7) + (cq << 3)];
  }
}

// ------- fused conv(4)+SiLU+x_proj+dt_proj+local scan (chunk = 32-row tile) ----------
__global__ __launch_bounds__(384) void k_convx(const unsigned short* __restrict__ xin,
                                               const float* __restrict__ cw,
                                               const float* __restrict__ cb,
                                               const unsigned short* __restrict__ W,
                                               const float* __restrict__ dw,
                                               const float* __restrict__ dbias,
                                               const float* __restrict__ A_log,
                                               unsigned short* __restrict__ xsb,
                                               float* __restrict__ dbl,
                                               unsigned short* __restrict__ dtb,
                                               unsigned short* __restrict__ Hloc,
                                               float* __restrict__ Sbuf) {
  __shared__ unsigned short xs[6 * 2048];  // 6 K-tiles [32 rows][64 cols], XOR-swizzled
  __shared__ unsigned short Bs[2][3072];   // W tile 48 x 64, double-buffered
  __shared__ float dl[CSZ][12];            // dbl cols 0..11 for dt_proj
  __shared__ float Bsh2[CSZ][16];          // dbl cols 12..27 (B matrix)
  int tid = threadIdx.x;
  int w = tid >> 6, l = tid & 63;
  int b = blockIdx.y;
  int chunk = blockIdx.x;       // 0..127
  int l0 = chunk << 5;
  int d = tid;  // 0..383
  // ---- phase 1: conv + SiLU ----
  float4 w4 = *(const float4*)&cw[d * 4];
  float bb = cb[d];
  const unsigned short* xp = xin + ((size_t)b * L_ + l0) * DI + d;
  unsigned short* op = xsb + ((size_t)b * L_ + l0) * DI + d;
  float x0 = 0.f, x1 = 0.f, x2 = 0.f;
  if (l0 > 0) {
    x0 = bf2f(*(xp - 3 * DI));
    x1 = bf2f(*(xp - 2 * DI));
    x2 = bf2f(*(xp - DI));
  }
  int kt = d >> 6, col = d & 63, g = col >> 3, e = col & 7;
  unsigned short* xsrow = xs + kt * 2048;
  for (int r = 0; r < 32; ++r) {
    float xv = bf2f(xp[(size_t)r * DI]);
    float a = bb + w4.x * x0 + w4.y * x1 + w4.z * x2 + w4.w * xv;
    float sv = a * __builtin_amdgcn_rcpf(1.f + __expf(-a));
    unsigned short sb = f2bf(sv);
    xsrow[r * 64 + ((g ^ (r & 7)) << 3) + e] = sb;
    op[(size_t)r * DI] = sb;
    x0 = x1; x1 = x2; x2 = xv;
  }
  __syncthreads();
  // ---- phase 2: x_proj MFMA, 6-wave (mt x nt), dbuf W staging ----
  int lr = l & 15, lk = l >> 4;
  int mt = w & 1, nt = w >> 1;   // 2 m-tiles x 3 n-tiles
  {
    int row = tid >> 3;  // 0..47
    int gc = (((tid & 7) ^ (row & 7)) << 3);
    gload16(W + (size_t)row * 384 + gc, &Bs[0][w << 9]);
  }
  f32x4 accx = (f32x4){0.f, 0.f, 0.f, 0.f};
  for (int kt2 = 0; kt2 < 6; ++kt2) {
    __syncthreads();  // drains staged buf (kt2&1) + (kt2=0) xs writes
    if (kt2 < 5) {
      int k0 = (kt2 + 1) * 64;
      int row = tid >> 3;
      int gc = k0 + (((tid & 7) ^ (row & 7)) << 3);
      gload16(W + (size_t)row * 384 + gc, &Bs[(kt2 + 1) & 1][w << 9]);
    }
    const unsigned short* Bcur = Bs[kt2 & 1];
#pragma unroll
    for (int ks = 0; ks < 2; ++ks) {
      int s = (ks << 2) + lk;
      int ar = (mt << 4) + lr;
      bf16x8 a = *(const bf16x8*)&xs[kt2 * 2048 + ar * 64 + ((s ^ (ar & 7)) << 3)];
      int br = (nt << 4) + lr;
      bf16x8 bbv = *(const bf16x8*)&Bcur[br * 64 + ((s ^ (br & 7)) << 3)];
      accx = MFMA16(a, bbv, accx);
    }
  }
  // ---- phase 3: scatter dbl to global + LDS (dl/Bsh2), all 6 waves ----
  {
    int colq = (nt << 4) + lr;
#pragma unroll
    for (int r = 0; r < 4; ++r) {
      int row = (mt << 4) + (lk << 2) + r;
      float v = accx[r];
      if (colq < NDBL) dbl[((size_t)b * L_ + l0 + row) * NDBL + colq] = v;
      if (colq < 12) dl[row][colq] = v;
      else if (colq < 28) Bsh2[row][colq - 12] = v;
    }
  }
  __syncthreads();
  // ---- phase 4: dt_proj + chunk-local scan ----
  float4 wv0 = *(const float4*)&dw[d * 12];
  float4 wv1 = *(const float4*)&dw[d * 12 + 4];
  float4 wv2 = *(const float4*)&dw[d * 12 + 8];
  float bias = dbias[d];
  bool fast = true;
#pragma unroll
  for (int n = 0; n < 16; ++n) {
    float An_ = -__expf(A_log[d * 16 + n]);
    fast = fast && (fabsf(An_ + (float)(n + 1)) < 2e-3f);
  }
  unsigned short* dtp = dtb + ((size_t)b * L_ + l0) * DI + d;
  float h[16];
#pragma unroll
  for (int n = 0; n < 16; ++n) h[n] = 0.f;
  float S = 0.f;
  if (fast) {
#pragma unroll
    for (int i = 0; i < CSZ; ++i) {
      float4 c0 = *(const float4*)&dl[i][0];
      float4 c1 = *(const float4*)&dl[i][4];
      float4 c2 = *(const float4*)&dl[i][8];
      float a = bias;
      a = fmaf(wv0.x, c0.x, a); a = fmaf(wv0.y, c0.y, a);
      a = fmaf(wv0.z, c0.z, a); a = fmaf(wv0.w, c0.w, a);
      a = fmaf(wv1.x, c1.x, a); a = fmaf(wv1.y, c1.y, a);
      a = fmaf(wv1.z, c1.z, a); a = fmaf(wv1.w, c1.w, a);
      a = fmaf(wv2.x, c2.x, a); a = fmaf(wv2.y, c2.y, a);
      a = fmaf(wv2.z, c2.z, a); a = fmaf(wv2.w, c2.w, a);
      float sp = fmaxf(a, 0.f) + __logf(1.f + __expf(-fabsf(a)));
      dtp[(size_t)i * DI] = f2bf(sp);
      S += sp;
      float xv = bf2f(xsrow[i * 64 + ((g ^ (i & 7)) << 3) + e]);
      float dtx = sp * xv;
      float r = __expf(-sp);
      float r2 = r * r;
      float r4 = r2 * r2;
      float dA0 = r, dA1 = r2, dA2 = r2 * r, dA3 = r4;
#pragma unroll
      for (int gg = 0; gg < 4; ++gg) {
        float4 Bg = *(const float4*)&Bsh2[i][gg << 2];
        h[(gg << 2) + 0] = fmaf(dA0, h[(gg << 2) + 0], dtx * Bg.x);
        h[(gg << 2) + 1] = fmaf(dA1, h[(gg << 2) + 1], dtx * Bg.y);
        h[(gg << 2) + 2] = fmaf(dA2, h[(gg << 2) + 2], dtx * Bg.z);
        h[(gg << 2) + 3] = fmaf(dA3, h[(gg << 2) + 3], dtx * Bg.w);
        if (gg < 3) { dA0 *= r4; dA1 *= r4; dA2 *= r4; dA3 *= r4; }
      }
    }
  } else {
    float An[16];
#pragma unroll
    for (int n = 0; n < 16; ++n) An[n] = -__expf(A_log[d * 16 + n]);
#pragma unroll
    for (int i = 0; i < CSZ; ++i) {
      float4 c0 = *(const float4*)&dl[i][0];
      float4 c1 = *(const float4*)&dl[i][4];
      float4 c2 = *(const float4*)&dl[i][8];
      float a = bias;
      a = fmaf(wv0.x, c0.x, a); a = fmaf(wv0.y, c0.y, a);
      a = fmaf(wv0.z, c0.z, a); a = fmaf(wv0.w, c0.w, a);
      a = fmaf(wv1.x, c1.x, a); a = fmaf(wv1.y, c1.y, a);
      a = fmaf(wv1.z, c1.z, a); a = fmaf(wv1.w, c1.w, a);
      a = fmaf(wv2.x, c2.x, a); a = fmaf(wv2.y, c2.y, a);
      a = fmaf(wv2.z, c2.z, a); a = fmaf(wv2.w, c2.w, a);
      float sp = fmaxf(a, 0.f) + __logf(1.f + __expf(-fabsf(a)));
      dtp[(size_t)i * DI] = f2bf(sp);
      S += sp;
      float xv = bf2f(xsrow[i * 64 + ((g ^ (i & 7)) << 3) + e]);
      float dtx = sp * xv;
#pragma unroll
      for (int n = 0; n < 16; ++n)
        h[n] = fmaf(__expf(sp * An[n]), h[n], dtx * Bsh2[i][n]);
    }
  }
  size_t hbase = ((size_t)(b * NCHUNK + chunk) * 16) * DI + d;
#pragma unroll
  for (int n = 0; n < 16; ++n) Hloc[hbase + (size_t)n * DI] = f2bf(h[n]);
  Sbuf[((size_t)b * NCHUNK + chunk) * DI + d] = S;
}

// ---------------- scan pass B1: per-super local prefix (in-place) + super totals -----
__global__ __launch_bounds__(384) void k_scanB1(const float* __restrict__ A_log,
                                                unsigned short* __restrict__ Hloc,
                                                const float* __restrict__ Sbuf,
                                                float* __restrict__ Spre,
                                                float* __restrict__ Hsup,
                                                float* __restrict__ Ssup) {
  int d = threadIdx.x;
  int blk = blockIdx.x;   // 512: b*128 + s*16 + n
  int n = blk & 15;
  int s = (blk >> 4) & 7;
  int b = blk >> 7;
  float An = -__expf(A_log[d * 16 + n]);
  float h = 0.f, Sp = 0.f;
  int c0 = s * 16;
#pragma unroll
  for (int i = 0; i < 16; ++i) {
    int c = c0 + i;
    size_t hidx = (((size_t)(b * NCHUNK + c) * 16) + n) * DI + d;
    float Hl = bf2f(Hloc[hidx]);
    float S = Sbuf[((size_t)b * NCHUNK + c) * DI + d];
    Hloc[hidx] = f2bf(h);
    if (n == 0) Spre[((size_t)b * NCHUNK + c) * DI + d] = Sp;
    h = fmaf(__expf(An * S), h, Hl);
    Sp += S;
  }
  Hsup[(((size_t)(b * NSUP + s) * 16) + n) * DI + d] = h;
  if (n == 0) Ssup[((size_t)b * NSUP + s) * DI + d] = Sp;
}

// ----- scan pass C: inline super-carry + local scan + gating + fused out_proj --------
__global__ __launch_bounds__(384) void k_scanC(const unsigned short* __restrict__ xsb,
                                               const unsigned short* __restrict__ dtb,
                                               const float* __restrict__ dbl,
                                               const unsigned short* __restrict__ z,
                                               const float* __restrict__ A_log,
                                               const float* __restrict__ Dw,
                                               const unsigned short* __restrict__ Hloc,
                                               const float* __restrict__ Spre,
                                               const float* __restrict__ Hsup,
                                               const float* __restrict__ Ssup,
                                               const unsigned short* __restrict__ Wo,
                                               const float* __restrict__ x,
                                               float* __restrict__ out) {
  __shared__ float BCsh[CSZ][32];          // [r][0:16]=B, [r][16:32]=C
  __shared__ unsigned short yt[6 * 2048];  // y tile 32 x 384 bf16, 6 K-subtiles swizzled
  __shared__ unsigned short Bs[2][12288];  // W tile 192 x 64, double-buffered
  int tid = threadIdx.x;
  int blk = blockIdx.x;    // 512
  int b = blk >> 7;
  int chunk = blk & (NCHUNK - 1);
  int l0 = chunk << 5;
  for (int idx = tid; idx < CSZ * 32; idx += 384) {
    int r = idx >> 5, n32 = idx & 31;
    BCsh[r][n32] = dbl[((size_t)b * L_ + l0 + r) * NDBL + DTR + n32];
  }
  int d = tid;
  float Dd = Dw[d];
  bool fast = true;
#pragma unroll
  for (int n = 0; n < 16; ++n) {
    float An_ = -__expf(A_log[d * 16 + n]);
    fast = fast && (fabsf(An_ + (float)(n + 1)) < 2e-3f);
  }
  int sup = chunk >> 4;
  size_t hbase = ((size_t)(b * NCHUNK + chunk) * 16) * DI + d;
  float Spv = Spre[((size_t)b * NCHUNK + chunk) * DI + d];
  float h[16];
  if (fast) {
    // inline super-carry: I[n] over supers 0..sup-1
    float I[16];
#pragma unroll
    for (int n = 0; n < 16; ++n) I[n] = 0.f;
    for (int s = 0; s < sup; ++s) {
      float Ss = Ssup[((size_t)b * NSUP + s) * DI + d];
      const float* Hs = Hsup + ((size_t)(b * NSUP + s) * 16) * DI + d;
      float t = __expf(-Ss);
      float t2 = t * t, t4 = t2 * t2;
      float p0 = t, p1 = t2, p2 = t2 * t, p3 = t4;
#pragma unroll
      for (int gI = 0; gI < 4; ++gI) {
        I[(gI << 2) + 0] = fmaf(p0, I[(gI << 2) + 0], Hs[(size_t)((gI << 2) + 0) * DI]);
        I[(gI << 2) + 1] = fmaf(p1, I[(gI << 2) + 1], Hs[(size_t)((gI << 2) + 1) * DI]);
        I[(gI << 2) + 2] = fmaf(p2, I[(gI << 2) + 2], Hs[(size_t)((gI << 2) + 2) * DI]);
        I[(gI << 2) + 3] = fmaf(p3, I[(gI << 2) + 3], Hs[(size_t)((gI << 2) + 3) * DI]);
        if (gI < 3) { p0 *= t4; p1 *= t4; p2 *= t4; p3 *= t4; }
      }
    }
    float t = __expf(-Spv);
    float t2 = t * t, t4 = t2 * t2;
    float p0 = t, p1 = t2, p2 = t2 * t, p3 = t4;
#pragma unroll
    for (int gI = 0; gI < 4; ++gI) {
      h[(gI << 2) + 0] = fmaf(p0, I[(gI << 2) + 0], bf2f(Hloc[hbase + (size_t)((gI << 2) + 0) * DI]));
      h[(gI << 2) + 1] = fmaf(p1, I[(gI << 2) + 1], bf2f(Hloc[hbase + (size_t)((gI << 2) + 1) * DI]));
      h[(gI << 2) + 2] = fmaf(p2, I[(gI << 2) + 2], bf2f(Hloc[hbase + (size_t)((gI << 2) + 2) * DI]));
      h[(gI << 2) + 3] = fmaf(p3, I[(gI << 2) + 3], bf2f(Hloc[hbase + (size_t)((gI << 2) + 3) * DI]));
      if (gI < 3) { p0 *= t4; p1 *= t4; p2 *= t4; p3 *= t4; }
    }
  } else {
    float An[16];
#pragma unroll
    for (int n = 0; n < 16; ++n) An[n] = -__expf(A_log[d * 16 + n]);
    float I[16];
#pragma unroll
    for (int n = 0; n < 16; ++n) I[n] = 0.f;
    for (int s = 0; s < sup; ++s) {
      float Ss = Ssup[((size_t)b * NSUP + s) * DI + d];
      const float* Hs = Hsup + ((size_t)(b * NSUP + s) * 16) * DI + d;
#pragma unroll
      for (int n = 0; n < 16; ++n)
        I[n] = fmaf(__expf(An[n] * Ss), I[n], Hs[(size_t)n * DI]);
    }
#pragma unroll
    for (int n = 0; n < 16; ++n)
      h[n] = fmaf(__expf(An[n] * Spv), I[n], bf2f(Hloc[hbase + (size_t)n * DI]));
  }
  const unsigned short* xp = xsb + ((size_t)b * L_ + l0) * DI + d;
  const unsigned short* dtp = dtb + ((size_t)b * L_ + l0) * DI + d;
  const unsigned short* zp = z + ((size_t)b * L_ + l0) * DI + d;
  int ktile = d >> 6, colq = d & 63, gq = colq >> 3, eq = colq & 7;
  unsigned short* ytp = yt + ktile * 2048;
  __syncthreads();
  if (fast) {
#pragma unroll
    for (int i = 0; i < CSZ; ++i) {
      float sp = bf2f(dtp[(size_t)i * DI]);
      float xv = bf2f(xp[(size_t)i * DI]);
      float zv = bf2f(zp[(size_t)i * DI]);
      float dtx = sp * xv;
      float r = __expf(-sp);
      float r2 = r * r;
      float r4 = r2 * r2;
      float dA0 = r, dA1 = r2, dA2 = r2 * r, dA3 = r4;
      float y = 0.f;
#pragma unroll
      for (int g = 0; g < 4; ++g) {
        float4 Bg = *(const float4*)&BCsh[i][g << 2];
        float4 Cg = *(const float4*)&BCsh[i][16 + (g << 2)];
        h[(g << 2) + 0] = fmaf(dA0, h[(g << 2) + 0], dtx * Bg.x);
        h[(g << 2) + 1] = fmaf(dA1, h[(g << 2) + 1], dtx * Bg.y);
        h[(g << 2) + 2] = fmaf(dA2, h[(g << 2) + 2], dtx * Bg.z);
        h[(g << 2) + 3] = fmaf(dA3, h[(g << 2) + 3], dtx * Bg.w);
        y = fmaf(h[(g << 2) + 0], Cg.x, y);
        y = fmaf(h[(g << 2) + 1], Cg.y, y);
        y = fmaf(h[(g << 2) + 2], Cg.z, y);
        y = fmaf(h[(g << 2) + 3], Cg.w, y);
        if (g < 3) { dA0 *= r4; dA1 *= r4; dA2 *= r4; dA3 *= r4; }
      }
      y = fmaf(xv, Dd, y);
      float sig = __builtin_amdgcn_rcpf(1.f + __expf(-zv));
      ytp[i * 64 + ((gq ^ (i & 7)) << 3) + eq] = f2bf(y * (zv * sig));
    }
  } else {
    float An[16];
#pragma unroll
    for (int n = 0; n < 16; ++n) An[n] = -__expf(A_log[d * 16 + n]);
#pragma unroll
    for (int i = 0; i < CSZ; ++i) {
      float sp = bf2f(dtp[(size_t)i * DI]);
      float xv = bf2f(xp[(size_t)i * DI]);
      float zv = bf2f(zp[(size_t)i * DI]);
      float dtx = sp * xv;
      float y = 0.f;
#pragma unroll
      for (int n = 0; n < 16; ++n) {
        h[n] = fmaf(__expf(sp * An[n]), h[n], dtx * BCsh[i][n]);
        y = fmaf(h[n], BCsh[i][16 + n], y);
      }
      y = fmaf(xv, Dd, y);
      float sig = __builtin_amdgcn_rcpf(1.f + __expf(-zv));
      ytp[i * 64 + ((gq ^ (i & 7)) << 3) + eq] = f2bf(y * (zv * sig));
    }
  }
  // ---- fused out_proj: out[32 x 192] = y(32x384) @ Wo(192,384)^T + x; dbuf W ----
  int w = tid >> 6, l = tid & 63;
  int lr = l & 15, lk = l >> 4;
  int mt = w & 1;          // m-tile 0/1
  int ng = w >> 1;         // n-group 0..2 (4 n-tiles each)
  {
#pragma unroll
    for (int j = 0; j < 4; ++j) {
      int row = j * 48 + (tid >> 3);
      int gc = (((tid & 7) ^ (row & 7)) << 3);
      gload16(Wo + (size_t)row * 384 + gc, &Bs[0][j * 3072 + (w << 9)]);
    }
  }
  f32x4 acc[4];
#pragma unroll
  for (int j = 0; j < 4; ++j) acc[j] = (f32x4){0.f, 0.f, 0.f, 0.f};
  for (int kt = 0; kt < 6; ++kt) {
    __syncthreads();  // yt ready (kt=0) + staged buf (kt&1) drained
    if (kt < 5) {
      int k0 = (kt + 1) * 64;
#pragma unroll
      for (int j = 0; j < 4; ++j) {
        int row = j * 48 + (tid >> 3);
        int gc = k0 + (((tid & 7) ^ (row & 7)) << 3);
        gload16(Wo + (size_t)row * 384 + gc, &Bs[(kt + 1) & 1][j * 3072 + (w << 9)]);
      }
    }
    const unsigned short* Bcur = Bs[kt & 1];
#pragma unroll
    for (int ks = 0; ks < 2; ++ks) {
      int s = (ks << 2) + lk;
      bf16x8 a = *(const bf16x8*)&yt[kt * 2048 + (mt * 16 + lr) * 64 + ((s ^ (lr & 7)) << 3)];
#pragma unroll
      for (int j = 0; j < 4; ++j) {
        int br = (ng * 4 + j) * 16 + lr;
        bf16x8 bv = *(const bf16x8*)&Bcur[br * 64 + ((s ^ (br & 7)) << 3)];
        acc[j] = MFMA16(a, bv, acc[j]);
      }
    }
  }
#pragma unroll
  for (int j = 0; j < 4; ++j) {
    int c = (ng * 4 + j) * 16 + lr;
    size_t off = ((size_t)b * C_ + c) * L_ + l0 + mt * 16 + (lk << 2);
    f32x4 xv = *(const f32x4*)&x[off];
    *(f32x4*)&out[off] = acc[j] + xv;
  }
}

extern "C" void kernel_launch(void* const* d_in, const int* in_sizes, int n_in,
                              void* d_out, int out_size, void* d_ws, size_t ws_size,
                              hipStream_t stream) {
  const float* x         = (const float*)d_in[0];
  const float* norm_w    = (const float*)d_in[1];
  const float* norm_b    = (const float*)d_in[2];
  const float* in_proj_w = (const float*)d_in[3];
  const float* conv_w    = (const float*)d_in[4];
  const float* conv_b    = (const float*)d_in[5];
  const float* x_proj_w  = (const float*)d_in[6];
  const float* dt_proj_w = (const float*)d_in[7];
  const float* dt_proj_b = (const float*)d_in[8];
  const float* A_log     = (const float*)d_in[9];
  const float* Dw        = (const float*)d_in[10];
  const float* out_proj_w= (const float*)d_in[11];
  float* out = (float*)d_out;
  float* ws = (float*)d_ws;

  unsigned short* seqn = (unsigned short*)(ws + F_SEQN);
  unsigned short* xin  = (unsigned short*)(ws + F_XIN);
  unsigned short* z    = (unsigned short*)(ws + F_Z);
  unsigned short* xsb  = (unsigned short*)(ws + F_XSB);
  float* dbl           = ws + F_DBL;
  unsigned short* dtb  = (unsigned short*)(ws + F_DT);
  float* Sbuf          = ws + F_SBUF;
  unsigned short* Hloc = (unsigned short*)(ws + F_HLOC);
  float* Spre          = ws + F_SPRE;
  float* Hsup          = ws + F_HSUP;
  float* Ssup          = ws + F_SSUP;
  unsigned short* wbuf = (unsigned short*)(ws + F_WBUF);
  unsigned short* ipw  = wbuf;
  unsigned short* xpw  = wbuf + 147456;
  unsigned short* opw  = wbuf + 165888;

  hipLaunchKernelGGL(k_ln, dim3(1960), dim3(256), 0, stream, x, norm_w, norm_b, seqn,
                     in_proj_w, x_proj_w, out_proj_w, wbuf);
  hipLaunchKernelGGL(k_inproj, dim3(128, 6), dim3(256), 0, stream, seqn, ipw, xin, z);
  hipLaunchKernelGGL(k_convx, dim3(128, 4), dim3(384), 0, stream, xin, conv_w, conv_b, xpw,
                     dt_proj_w, dt_proj_b, A_log, xsb, dbl, dtb, Hloc, Sbuf);
  hipLaunchKernelGGL(k_scanB1, dim3(512), dim3(384), 0, stream, A_log, Hloc, Sbuf, Spre, Hsup,
                     Ssup);
  hipLaunchKernelGGL(k_scanC, dim3(512), dim3(384), 0, stream, xsb, dtb, dbl, z, A_log, Dw,
                     Hloc, Spre, Hsup, Ssup, opw, x, out);
}

// Round 13
// 96.530 us; speedup vs baseline: 1.0763x; 1.0763x over previous
//
#include <hip/hip_runtime.h>
#include <hip/hip_bf16.h>

// Problem constants
constexpr int B_ = 4;
constexpr int C_ = 192;
constexpr int L_ = 4096;     // H*W
constexpr int DI = 384;      // d_inner
constexpr int DSs = 16;      // d_state
constexpr int DTR = 12;      // dt_rank
constexpr int NDBL = 44;     // dt_rank + 2*d_state
constexpr int NCHUNK = 128;  // scan chunks
constexpr int CSZ = 32;      // chunk size (== convx tile rows)
constexpr int NSUP = 8;      // super-chunks (16 chunks each)

constexpr size_t BL = (size_t)B_ * L_;  // 16384

// Workspace offsets in FLOAT units (bf16 buffers counted at half)
constexpr size_t F_SEQN = 0;                                   // bf16 BL*C
constexpr size_t F_XIN  = F_SEQN + BL * C_ / 2;                // bf16 BL*DI
constexpr size_t F_Z    = F_XIN + BL * DI / 2;                 // bf16 BL*DI
constexpr size_t F_XSB  = F_Z + BL * DI / 2;                   // bf16 BL*DI
constexpr size_t F_DBL  = F_XSB + BL * DI / 2;                 // f32  BL*NDBL
constexpr size_t F_DT   = F_DBL + BL * NDBL;                   // bf16 BL*DI
constexpr size_t F_SBUF = F_DT + BL * DI / 2;                  // f32  B*NCHUNK*DI
constexpr size_t F_HLOC = F_SBUF + (size_t)B_ * NCHUNK * DI;   // bf16 B*NCHUNK*16*DI
constexpr size_t F_SPRE = F_HLOC + (size_t)B_ * NCHUNK * DI * 16 / 2;  // f32 B*NCHUNK*DI
constexpr size_t F_HSUP = F_SPRE + (size_t)B_ * NCHUNK * DI;   // f32 B*NSUP*16*DI
constexpr size_t F_SSUP = F_HSUP + (size_t)B_ * NSUP * 16 * DI;// f32 B*NSUP*DI
constexpr size_t F_ISUP = F_SSUP + (size_t)B_ * NSUP * DI;     // f32 (unused)
constexpr size_t F_WBUF = F_ISUP + (size_t)B_ * NSUP * 16 * DI;// bf16 weights
// total ~= 70 MB (prior rounds used 129 MB: safe)

typedef __attribute__((ext_vector_type(8))) short bf16x8;
typedef __attribute__((ext_vector_type(4))) float f32x4;

__device__ __forceinline__ unsigned short f2bf(float v) {
  unsigned x = __builtin_bit_cast(unsigned, v);
  unsigned r = x + 0x7FFFu + ((x >> 16) & 1u);   // RNE
  return (unsigned short)(r >> 16);
}
__device__ __forceinline__ float bf2f(unsigned short u) {
  return __builtin_bit_cast(float, (unsigned)u << 16);
}
__device__ __forceinline__ void gload16(const void* g, void* l) {
  __builtin_amdgcn_global_load_lds((const __attribute__((address_space(1))) void*)g,
                                   (__attribute__((address_space(3))) void*)l, 16, 0, 0);
}
#define MFMA16(a, b, c) __builtin_amdgcn_mfma_f32_16x16x32_bf16(a, b, c, 0, 0, 0)

// ---------------- LayerNorm (blocks 0..1023, 16-row tiles) + weight cvt tail ---------
__global__ __launch_bounds__(256) void k_ln(const float* __restrict__ x,
                                            const float* __restrict__ nw,
                                            const float* __restrict__ nb,
                                            unsigned short* __restrict__ seqn,
                                            const float* __restrict__ ipw,
                                            const float* __restrict__ xpw,
                                            const float* __restrict__ opw,
                                            unsigned short* __restrict__ wbuf) {
  if (blockIdx.x >= 1024) {
    int t = (blockIdx.x - 1024) * 256 + threadIdx.x;
    if (t < 239616) {
      float v;
      if (t < 147456) v = ipw[t];
      else if (t < 165888) {
        int j = t - 147456;
        int r = j / 384, c = j - r * 384;
        v = (r < 44) ? xpw[r * 384 + c] : 0.f;
      } else v = opw[t - 165888];
      wbuf[t] = f2bf(v);
    }
    return;
  }
  __shared__ unsigned short xt[192][18];
  __shared__ float ps[16][16], ps2[16][16];
  __shared__ float mu_[16], rs_[16];
  __shared__ float wsh[192], bsh[192];
  int tid = threadIdx.x;
  int blk = blockIdx.x;          // 0..1023
  int b = blk >> 8;
  int l0 = (blk & 255) << 4;
  const float* xb = x + (size_t)b * C_ * L_;
  for (int idx = tid; idx < 192 * 4; idx += 256) {
    int c = idx >> 2, lq = idx & 3;
    float4 v = *(const float4*)&xb[(size_t)c * L_ + l0 + (lq << 2)];
    ushort2 u0, u1;
    u0.x = f2bf(v.x); u0.y = f2bf(v.y);
    u1.x = f2bf(v.z); u1.y = f2bf(v.w);
    *(ushort2*)&xt[c][(lq << 2)] = u0;
    *(ushort2*)&xt[c][(lq << 2) + 2] = u1;
  }
  if (tid < 192) { wsh[tid] = nw[tid]; bsh[tid] = nb[tid]; }
  __syncthreads();
  int ll = tid & 15, q = tid >> 4;   // 16 groups x 12 channels
  float s = 0.f, ss = 0.f;
  for (int c = q * 12; c < q * 12 + 12; ++c) {
    float v = bf2f(xt[c][ll]);
    s += v; ss += v * v;
  }
  ps[q][ll] = s; ps2[q][ll] = ss;
  __syncthreads();
  if (q == 0) {
    float st = 0.f, sst = 0.f;
#pragma unroll
    for (int g = 0; g < 16; ++g) { st += ps[g][ll]; sst += ps2[g][ll]; }
    float mu = st * (1.f / 192.f);
    float var = sst * (1.f / 192.f) - mu * mu;
    mu_[ll] = mu; rs_[ll] = rsqrtf(var + 1e-5f);
  }
  __syncthreads();
  unsigned short* so = seqn + ((size_t)b * L_ + l0) * C_;
  for (int idx = tid; idx < 16 * 192; idx += 256) {
    int l = idx / 192, c = idx - l * 192;
    so[idx] = f2bf((bf2f(xt[c][l]) - mu_[l]) * rs_[l] * wsh[c] + bsh[c]);
  }
}

// ---------------- in_proj MFMA: seqn(BL,192)bf16 @ W(768,192)^T -> xin,z bf16 --------
__global__ __launch_bounds__(256) void k_inproj(const unsigned short* __restrict__ A,
                                                const unsigned short* __restrict__ W,
                                                unsigned short* __restrict__ xin,
                                                unsigned short* __restrict__ z) {
  __shared__ unsigned short smem[16384];
  unsigned short* As = smem;
  unsigned short* Bs = smem + 8192;
  int tid = threadIdx.x;
  int w = tid >> 6, l = tid & 63;
  int wr = w >> 1, wc = w & 1;
  int m0 = blockIdx.x << 7;
  int n0 = blockIdx.y << 7;
  f32x4 acc[4][4];
#pragma unroll
  for (int i = 0; i < 4; ++i)
#pragma unroll
    for (int j = 0; j < 4; ++j) acc[i][j] = (f32x4){0.f, 0.f, 0.f, 0.f};
  int lr = l & 15, lk = l >> 4;
  for (int kt = 0; kt < 3; ++kt) {
    int k0 = kt * 64;
    if (kt) __syncthreads();
#pragma unroll
    for (int i = 0; i < 4; ++i) {
      int row = (i << 5) + (tid >> 3);
      int gc = k0 + (((tid & 7) ^ (row & 7)) << 3);
      gload16(A + (size_t)(m0 + row) * 192 + gc, &As[(i << 11) + (w << 9)]);
      gload16(W + (size_t)(n0 + row) * 192 + gc, &Bs[(i << 11) + (w << 9)]);
    }
    __syncthreads();
#pragma unroll
    for (int ks = 0; ks < 2; ++ks) {
      int s = (ks << 2) + lk;
      bf16x8 af[4], bfr[4];
#pragma unroll
      for (int mi = 0; mi < 4; ++mi) {
        int r = (wr << 6) + (mi << 4) + lr;
        af[mi] = *(const bf16x8*)&As[r * 64 + ((s ^ (r & 7)) << 3)];
      }
#pragma unroll
      for (int ni = 0; ni < 4; ++ni) {
        int r = (wc << 6) + (ni << 4) + lr;
        bfr[ni] = *(const bf16x8*)&Bs[r * 64 + ((s ^ (r & 7)) << 3)];
      }
#pragma unroll
      for (int mi = 0; mi < 4; ++mi)
#pragma unroll
        for (int ni = 0; ni < 4; ++ni) acc[mi][ni] = MFMA16(af[mi], bfr[ni], acc[mi][ni]);
    }
  }
  __syncthreads();
#pragma unroll
  for (int mi = 0; mi < 4; ++mi)
#pragma unroll
    for (int ni = 0; ni < 4; ++ni) {
      int col = (wc << 6) + (ni << 4) + lr;
#pragma unroll
      for (int r = 0; r < 4; ++r) {
        int row = (wr << 6) + (mi << 4) + (lk << 2) + r;
        smem[(row << 7) + col] = f2bf(acc[mi][ni][r]);
      }
    }
  __syncthreads();
#pragma unroll
  for (int i = 0; i < 8; ++i) {
    int chunk = i * 256 + tid;
    int row = chunk >> 4, cq = chunk & 15;
    int n = n0 + (cq << 3);
    unsigned short* dst = (n < 384) ? (xin + (size_t)(m0 + row) * DI + n)
                                    : (z + (size_t)(m0 + row) * DI + (n - 384));
    *(bf16x8*)dst = *(const bf16x8*)&smem[(row << 7) + (cq << 3)];
  }
}

// ------- fused conv(4)+SiLU+x_proj+dt_proj+local scan (chunk = 32-row tile) ----------
__global__ __launch_bounds__(384) void k_convx(const unsigned short* __restrict__ xin,
                                               const float* __restrict__ cw,
                                               const float* __restrict__ cb,
                                               const unsigned short* __restrict__ W,
                                               const float* __restrict__ dw,
                                               const float* __restrict__ dbias,
                                               const float* __restrict__ A_log,
                                               unsigned short* __restrict__ xsb,
                                               float* __restrict__ dbl,
                                               unsigned short* __restrict__ dtb,
                                               unsigned short* __restrict__ Hloc,
                                               float* __restrict__ Sbuf) {
  __shared__ unsigned short xs[6 * 2048];  // 6 K-tiles [32 rows][64 cols], XOR-swizzled
  __shared__ unsigned short Bs[2][3072];   // W tile 48 x 64, double-buffered
  __shared__ float dl[CSZ][12];            // dbl cols 0..11 for dt_proj
  __shared__ float Bsh2[CSZ][16];          // dbl cols 12..27 (B matrix)
  int tid = threadIdx.x;
  int w = tid >> 6, l = tid & 63;
  int b = blockIdx.y;
  int chunk = blockIdx.x;       // 0..127
  int l0 = chunk << 5;
  int d = tid;  // 0..383
  // ---- phase 1: conv + SiLU ----
  float4 w4 = *(const float4*)&cw[d * 4];
  float bb = cb[d];
  const unsigned short* xp = xin + ((size_t)b * L_ + l0) * DI + d;
  unsigned short* op = xsb + ((size_t)b * L_ + l0) * DI + d;
  float x0 = 0.f, x1 = 0.f, x2 = 0.f;
  if (l0 > 0) {
    x0 = bf2f(*(xp - 3 * DI));
    x1 = bf2f(*(xp - 2 * DI));
    x2 = bf2f(*(xp - DI));
  }
  int kt = d >> 6, col = d & 63, g = col >> 3, e = col & 7;
  unsigned short* xsrow = xs + kt * 2048;
  for (int r = 0; r < 32; ++r) {
    float xv = bf2f(xp[(size_t)r * DI]);
    float a = bb + w4.x * x0 + w4.y * x1 + w4.z * x2 + w4.w * xv;
    float sv = a * __builtin_amdgcn_rcpf(1.f + __expf(-a));
    unsigned short sb = f2bf(sv);
    xsrow[r * 64 + ((g ^ (r & 7)) << 3) + e] = sb;
    op[(size_t)r * DI] = sb;
    x0 = x1; x1 = x2; x2 = xv;
  }
  __syncthreads();
  // ---- phase 2: x_proj MFMA, 6-wave (mt x nt), dbuf W staging ----
  int lr = l & 15, lk = l >> 4;
  int mt = w & 1, nt = w >> 1;   // 2 m-tiles x 3 n-tiles
  {
    int row = tid >> 3;  // 0..47
    int gc = (((tid & 7) ^ (row & 7)) << 3);
    gload16(W + (size_t)row * 384 + gc, &Bs[0][w << 9]);
  }
  f32x4 accx = (f32x4){0.f, 0.f, 0.f, 0.f};
  for (int kt2 = 0; kt2 < 6; ++kt2) {
    __syncthreads();  // drains staged buf (kt2&1) + (kt2=0) xs writes
    if (kt2 < 5) {
      int k0 = (kt2 + 1) * 64;
      int row = tid >> 3;
      int gc = k0 + (((tid & 7) ^ (row & 7)) << 3);
      gload16(W + (size_t)row * 384 + gc, &Bs[(kt2 + 1) & 1][w << 9]);
    }
    const unsigned short* Bcur = Bs[kt2 & 1];
#pragma unroll
    for (int ks = 0; ks < 2; ++ks) {
      int s = (ks << 2) + lk;
      int ar = (mt << 4) + lr;
      bf16x8 a = *(const bf16x8*)&xs[kt2 * 2048 + ar * 64 + ((s ^ (ar & 7)) << 3)];
      int br = (nt << 4) + lr;
      bf16x8 bbv = *(const bf16x8*)&Bcur[br * 64 + ((s ^ (br & 7)) << 3)];
      accx = MFMA16(a, bbv, accx);
    }
  }
  // ---- phase 3: scatter dbl to global + LDS (dl/Bsh2), all 6 waves ----
  {
    int colq = (nt << 4) + lr;
#pragma unroll
    for (int r = 0; r < 4; ++r) {
      int row = (mt << 4) + (lk << 2) + r;
      float v = accx[r];
      if (colq < NDBL) dbl[((size_t)b * L_ + l0 + row) * NDBL + colq] = v;
      if (colq < 12) dl[row][colq] = v;
      else if (colq < 28) Bsh2[row][colq - 12] = v;
    }
  }
  __syncthreads();
  // ---- phase 4: dt_proj + chunk-local scan ----
  float4 wv0 = *(const float4*)&dw[d * 12];
  float4 wv1 = *(const float4*)&dw[d * 12 + 4];
  float4 wv2 = *(const float4*)&dw[d * 12 + 8];
  float bias = dbias[d];
  bool fast = true;
#pragma unroll
  for (int n = 0; n < 16; ++n) {
    float An_ = -__expf(A_log[d * 16 + n]);
    fast = fast && (fabsf(An_ + (float)(n + 1)) < 2e-3f);
  }
  unsigned short* dtp = dtb + ((size_t)b * L_ + l0) * DI + d;
  float h[16];
#pragma unroll
  for (int n = 0; n < 16; ++n) h[n] = 0.f;
  float S = 0.f;
  if (fast) {
#pragma unroll
    for (int i = 0; i < CSZ; ++i) {
      float4 c0 = *(const float4*)&dl[i][0];
      float4 c1 = *(const float4*)&dl[i][4];
      float4 c2 = *(const float4*)&dl[i][8];
      float a = bias;
      a = fmaf(wv0.x, c0.x, a); a = fmaf(wv0.y, c0.y, a);
      a = fmaf(wv0.z, c0.z, a); a = fmaf(wv0.w, c0.w, a);
      a = fmaf(wv1.x, c1.x, a); a = fmaf(wv1.y, c1.y, a);
      a = fmaf(wv1.z, c1.z, a); a = fmaf(wv1.w, c1.w, a);
      a = fmaf(wv2.x, c2.x, a); a = fmaf(wv2.y, c2.y, a);
      a = fmaf(wv2.z, c2.z, a); a = fmaf(wv2.w, c2.w, a);
      float sp = fmaxf(a, 0.f) + __logf(1.f + __expf(-fabsf(a)));
      dtp[(size_t)i * DI] = f2bf(sp);
      S += sp;
      float xv = bf2f(xsrow[i * 64 + ((g ^ (i & 7)) << 3) + e]);
      float dtx = sp * xv;
      float r = __expf(-sp);
      float r2 = r * r;
      float r4 = r2 * r2;
      float dA0 = r, dA1 = r2, dA2 = r2 * r, dA3 = r4;
#pragma unroll
      for (int gg = 0; gg < 4; ++gg) {
        float4 Bg = *(const float4*)&Bsh2[i][gg << 2];
        h[(gg << 2) + 0] = fmaf(dA0, h[(gg << 2) + 0], dtx * Bg.x);
        h[(gg << 2) + 1] = fmaf(dA1, h[(gg << 2) + 1], dtx * Bg.y);
        h[(gg << 2) + 2] = fmaf(dA2, h[(gg << 2) + 2], dtx * Bg.z);
        h[(gg << 2) + 3] = fmaf(dA3, h[(gg << 2) + 3], dtx * Bg.w);
        if (gg < 3) { dA0 *= r4; dA1 *= r4; dA2 *= r4; dA3 *= r4; }
      }
    }
  } else {
    float An[16];
#pragma unroll
    for (int n = 0; n < 16; ++n) An[n] = -__expf(A_log[d * 16 + n]);
#pragma unroll
    for (int i = 0; i < CSZ; ++i) {
      float4 c0 = *(const float4*)&dl[i][0];
      float4 c1 = *(const float4*)&dl[i][4];
      float4 c2 = *(const float4*)&dl[i][8];
      float a = bias;
      a = fmaf(wv0.x, c0.x, a); a = fmaf(wv0.y, c0.y, a);
      a = fmaf(wv0.z, c0.z, a); a = fmaf(wv0.w, c0.w, a);
      a = fmaf(wv1.x, c1.x, a); a = fmaf(wv1.y, c1.y, a);
      a = fmaf(wv1.z, c1.z, a); a = fmaf(wv1.w, c1.w, a);
      a = fmaf(wv2.x, c2.x, a); a = fmaf(wv2.y, c2.y, a);
      a = fmaf(wv2.z, c2.z, a); a = fmaf(wv2.w, c2.w, a);
      float sp = fmaxf(a, 0.f) + __logf(1.f + __expf(-fabsf(a)));
      dtp[(size_t)i * DI] = f2bf(sp);
      S += sp;
      float xv = bf2f(xsrow[i * 64 + ((g ^ (i & 7)) << 3) + e]);
      float dtx = sp * xv;
#pragma unroll
      for (int n = 0; n < 16; ++n)
        h[n] = fmaf(__expf(sp * An[n]), h[n], dtx * Bsh2[i][n]);
    }
  }
  size_t hbase = ((size_t)(b * NCHUNK + chunk) * 16) * DI + d;
#pragma unroll
  for (int n = 0; n < 16; ++n) Hloc[hbase + (size_t)n * DI] = f2bf(h[n]);
  Sbuf[((size_t)b * NCHUNK + chunk) * DI + d] = S;
}

// ---------------- scan pass B1: per-super local prefix (in-place) + super totals -----
__global__ __launch_bounds__(384) void k_scanB1(const float* __restrict__ A_log,
                                                unsigned short* __restrict__ Hloc,
                                                const float* __restrict__ Sbuf,
                                                float* __restrict__ Spre,
                                                float* __restrict__ Hsup,
                                                float* __restrict__ Ssup) {
  int d = threadIdx.x;
  int blk = blockIdx.x;   // 512: b*128 + s*16 + n
  int n = blk & 15;
  int s = (blk >> 4) & 7;
  int b = blk >> 7;
  float An = -__expf(A_log[d * 16 + n]);
  float h = 0.f, Sp = 0.f;
  int c0 = s * 16;
#pragma unroll
  for (int i = 0; i < 16; ++i) {
    int c = c0 + i;
    size_t hidx = (((size_t)(b * NCHUNK + c) * 16) + n) * DI + d;
    float Hl = bf2f(Hloc[hidx]);
    float S = Sbuf[((size_t)b * NCHUNK + c) * DI + d];
    Hloc[hidx] = f2bf(h);
    if (n == 0) Spre[((size_t)b * NCHUNK + c) * DI + d] = Sp;
    h = fmaf(__expf(An * S), h, Hl);
    Sp += S;
  }
  Hsup[(((size_t)(b * NSUP + s) * 16) + n) * DI + d] = h;
  if (n == 0) Ssup[((size_t)b * NSUP + s) * DI + d] = Sp;
}

// ----- scan pass C: inline super-carry + local scan + gating + fused out_proj --------
__global__ __launch_bounds__(384) void k_scanC(const unsigned short* __restrict__ xsb,
                                               const unsigned short* __restrict__ dtb,
                                               const float* __restrict__ dbl,
                                               const unsigned short* __restrict__ z,
                                               const float* __restrict__ A_log,
                                               const float* __restrict__ Dw,
                                               const unsigned short* __restrict__ Hloc,
                                               const float* __restrict__ Spre,
                                               const float* __restrict__ Hsup,
                                               const float* __restrict__ Ssup,
                                               const unsigned short* __restrict__ Wo,
                                               const float* __restrict__ x,
                                               float* __restrict__ out) {
  __shared__ float BCsh[CSZ][32];          // [r][0:16]=B, [r][16:32]=C
  __shared__ unsigned short yt[6 * 2048];  // y tile 32 x 384 bf16, 6 K-subtiles swizzled
  __shared__ unsigned short Bs[12288];     // W tile 192 x 64, single-buffered (52KB total)
  int tid = threadIdx.x;
  int blk = blockIdx.x;    // 512
  int b = blk >> 7;
  int chunk = blk & (NCHUNK - 1);
  int l0 = chunk << 5;
  // prefetch W tile for kt=0 immediately (hides under carry + scan phases)
  int w = tid >> 6, l = tid & 63;
#pragma unroll
  for (int j = 0; j < 4; ++j) {
    int row = j * 48 + (tid >> 3);
    int gc = (((tid & 7) ^ (row & 7)) << 3);
    gload16(Wo + (size_t)row * 384 + gc, &Bs[j * 3072 + (w << 9)]);
  }
  for (int idx = tid; idx < CSZ * 32; idx += 384) {
    int r = idx >> 5, n32 = idx & 31;
    BCsh[r][n32] = dbl[((size_t)b * L_ + l0 + r) * NDBL + DTR + n32];
  }
  int d = tid;
  float Dd = Dw[d];
  bool fast = true;
#pragma unroll
  for (int n = 0; n < 16; ++n) {
    float An_ = -__expf(A_log[d * 16 + n]);
    fast = fast && (fabsf(An_ + (float)(n + 1)) < 2e-3f);
  }
  int sup = chunk >> 4;
  size_t hbase = ((size_t)(b * NCHUNK + chunk) * 16) * DI + d;
  float Spv = Spre[((size_t)b * NCHUNK + chunk) * DI + d];
  float h[16];
  if (fast) {
    float I[16];
#pragma unroll
    for (int n = 0; n < 16; ++n) I[n] = 0.f;
    for (int s = 0; s < sup; ++s) {
      float Ss = Ssup[((size_t)b * NSUP + s) * DI + d];
      const float* Hs = Hsup + ((size_t)(b * NSUP + s) * 16) * DI + d;
      float t = __expf(-Ss);
      float t2 = t * t, t4 = t2 * t2;
      float p0 = t, p1 = t2, p2 = t2 * t, p3 = t4;
#pragma unroll
      for (int gI = 0; gI < 4; ++gI) {
        I[(gI << 2) + 0] = fmaf(p0, I[(gI << 2) + 0], Hs[(size_t)((gI << 2) + 0) * DI]);
        I[(gI << 2) + 1] = fmaf(p1, I[(gI << 2) + 1], Hs[(size_t)((gI << 2) + 1) * DI]);
        I[(gI << 2) + 2] = fmaf(p2, I[(gI << 2) + 2], Hs[(size_t)((gI << 2) + 2) * DI]);
        I[(gI << 2) + 3] = fmaf(p3, I[(gI << 2) + 3], Hs[(size_t)((gI << 2) + 3) * DI]);
        if (gI < 3) { p0 *= t4; p1 *= t4; p2 *= t4; p3 *= t4; }
      }
    }
    float t = __expf(-Spv);
    float t2 = t * t, t4 = t2 * t2;
    float p0 = t, p1 = t2, p2 = t2 * t, p3 = t4;
#pragma unroll
    for (int gI = 0; gI < 4; ++gI) {
      h[(gI << 2) + 0] = fmaf(p0, I[(gI << 2) + 0], bf2f(Hloc[hbase + (size_t)((gI << 2) + 0) * DI]));
      h[(gI << 2) + 1] = fmaf(p1, I[(gI << 2) + 1], bf2f(Hloc[hbase + (size_t)((gI << 2) + 1) * DI]));
      h[(gI << 2) + 2] = fmaf(p2, I[(gI << 2) + 2], bf2f(Hloc[hbase + (size_t)((gI << 2) + 2) * DI]));
      h[(gI << 2) + 3] = fmaf(p3, I[(gI << 2) + 3], bf2f(Hloc[hbase + (size_t)((gI << 2) + 3) * DI]));
      if (gI < 3) { p0 *= t4; p1 *= t4; p2 *= t4; p3 *= t4; }
    }
  } else {
    float An[16];
#pragma unroll
    for (int n = 0; n < 16; ++n) An[n] = -__expf(A_log[d * 16 + n]);
    float I[16];
#pragma unroll
    for (int n = 0; n < 16; ++n) I[n] = 0.f;
    for (int s = 0; s < sup; ++s) {
      float Ss = Ssup[((size_t)b * NSUP + s) * DI + d];
      const float* Hs = Hsup + ((size_t)(b * NSUP + s) * 16) * DI + d;
#pragma unroll
      for (int n = 0; n < 16; ++n)
        I[n] = fmaf(__expf(An[n] * Ss), I[n], Hs[(size_t)n * DI]);
    }
#pragma unroll
    for (int n = 0; n < 16; ++n)
      h[n] = fmaf(__expf(An[n] * Spv), I[n], bf2f(Hloc[hbase + (size_t)n * DI]));
  }
  const unsigned short* xp = xsb + ((size_t)b * L_ + l0) * DI + d;
  const unsigned short* dtp = dtb + ((size_t)b * L_ + l0) * DI + d;
  const unsigned short* zp = z + ((size_t)b * L_ + l0) * DI + d;
  int ktile = d >> 6, colq = d & 63, gq = colq >> 3, eq = colq & 7;
  unsigned short* ytp = yt + ktile * 2048;
  __syncthreads();
  if (fast) {
#pragma unroll
    for (int i = 0; i < CSZ; ++i) {
      float sp = bf2f(dtp[(size_t)i * DI]);
      float xv = bf2f(xp[(size_t)i * DI]);
      float zv = bf2f(zp[(size_t)i * DI]);
      float dtx = sp * xv;
      float r = __expf(-sp);
      float r2 = r * r;
      float r4 = r2 * r2;
      float dA0 = r, dA1 = r2, dA2 = r2 * r, dA3 = r4;
      float y = 0.f;
#pragma unroll
      for (int g = 0; g < 4; ++g) {
        float4 Bg = *(const float4*)&BCsh[i][g << 2];
        float4 Cg = *(const float4*)&BCsh[i][16 + (g << 2)];
        h[(g << 2) + 0] = fmaf(dA0, h[(g << 2) + 0], dtx * Bg.x);
        h[(g << 2) + 1] = fmaf(dA1, h[(g << 2) + 1], dtx * Bg.y);
        h[(g << 2) + 2] = fmaf(dA2, h[(g << 2) + 2], dtx * Bg.z);
        h[(g << 2) + 3] = fmaf(dA3, h[(g << 2) + 3], dtx * Bg.w);
        y = fmaf(h[(g << 2) + 0], Cg.x, y);
        y = fmaf(h[(g << 2) + 1], Cg.y, y);
        y = fmaf(h[(g << 2) + 2], Cg.z, y);
        y = fmaf(h[(g << 2) + 3], Cg.w, y);
        if (g < 3) { dA0 *= r4; dA1 *= r4; dA2 *= r4; dA3 *= r4; }
      }
      y = fmaf(xv, Dd, y);
      float sig = __builtin_amdgcn_rcpf(1.f + __expf(-zv));
      ytp[i * 64 + ((gq ^ (i & 7)) << 3) + eq] = f2bf(y * (zv * sig));
    }
  } else {
    float An[16];
#pragma unroll
    for (int n = 0; n < 16; ++n) An[n] = -__expf(A_log[d * 16 + n]);
#pragma unroll
    for (int i = 0; i < CSZ; ++i) {
      float sp = bf2f(dtp[(size_t)i * DI]);
      float xv = bf2f(xp[(size_t)i * DI]);
      float zv = bf2f(zp[(size_t)i * DI]);
      float dtx = sp * xv;
      float y = 0.f;
#pragma unroll
      for (int n = 0; n < 16; ++n) {
        h[n] = fmaf(__expf(sp * An[n]), h[n], dtx * BCsh[i][n]);
        y = fmaf(h[n], BCsh[i][16 + n], y);
      }
      y = fmaf(xv, Dd, y);
      float sig = __builtin_amdgcn_rcpf(1.f + __expf(-zv));
      ytp[i * 64 + ((gq ^ (i & 7)) << 3) + eq] = f2bf(y * (zv * sig));
    }
  }
  // ---- fused out_proj: out[32 x 192] = y(32x384) @ Wo(192,384)^T + x; single-buf W ----
  int lr = l & 15, lk = l >> 4;
  int mt = w & 1;          // m-tile 0/1
  int ng = w >> 1;         // n-group 0..2 (4 n-tiles each)
  f32x4 acc[4];
#pragma unroll
  for (int j = 0; j < 4; ++j) acc[j] = (f32x4){0.f, 0.f, 0.f, 0.f};
  for (int kt = 0; kt < 6; ++kt) {
    __syncthreads();  // kt=0: yt + prefetched W ready; kt>0: staged W ready
#pragma unroll
    for (int ks = 0; ks < 2; ++ks) {
      int s = (ks << 2) + lk;
      bf16x8 a = *(const bf16x8*)&yt[kt * 2048 + (mt * 16 + lr) * 64 + ((s ^ (lr & 7)) << 3)];
#pragma unroll
      for (int j = 0; j < 4; ++j) {
        int br = (ng * 4 + j) * 16 + lr;
        bf16x8 bv = *(const bf16x8*)&Bs[br * 64 + ((s ^ (br & 7)) << 3)];
        acc[j] = MFMA16(a, bv, acc[j]);
      }
    }
    if (kt < 5) {
      __syncthreads();  // drain this kt's MFMA reads before overwrite
      int k0 = (kt + 1) * 64;
#pragma unroll
      for (int j = 0; j < 4; ++j) {
        int row = j * 48 + (tid >> 3);
        int gc = k0 + (((tid & 7) ^ (row & 7)) << 3);
        gload16(Wo + (size_t)row * 384 + gc, &Bs[j * 3072 + (w << 9)]);
      }
    }
  }
#pragma unroll
  for (int j = 0; j < 4; ++j) {
    int c = (ng * 4 + j) * 16 + lr;
    size_t off = ((size_t)b * C_ + c) * L_ + l0 + mt * 16 + (lk << 2);
    f32x4 xv = *(const f32x4*)&x[off];
    *(f32x4*)&out[off] = acc[j] + xv;
  }
}

extern "C" void kernel_launch(void* const* d_in, const int* in_sizes, int n_in,
                              void* d_out, int out_size, void* d_ws, size_t ws_size,
                              hipStream_t stream) {
  const float* x         = (const float*)d_in[0];
  const float* norm_w    = (const float*)d_in[1];
  const float* norm_b    = (const float*)d_in[2];
  const float* in_proj_w = (const float*)d_in[3];
  const float* conv_w    = (const float*)d_in[4];
  const float* conv_b    = (const float*)d_in[5];
  const float* x_proj_w  = (const float*)d_in[6];
  const float* dt_proj_w = (const float*)d_in[7];
  const float* dt_proj_b = (const float*)d_in[8];
  const float* A_log     = (const float*)d_in[9];
  const float* Dw        = (const float*)d_in[10];
  const float* out_proj_w= (const float*)d_in[11];
  float* out = (float*)d_out;
  float* ws = (float*)d_ws;

  unsigned short* seqn = (unsigned short*)(ws + F_SEQN);
  unsigned short* xin  = (unsigned short*)(ws + F_XIN);
  unsigned short* z    = (unsigned short*)(ws + F_Z);
  unsigned short* xsb  = (unsigned short*)(ws + F_XSB);
  float* dbl           = ws + F_DBL;
  unsigned short* dtb  = (unsigned short*)(ws + F_DT);
  float* Sbuf          = ws + F_SBUF;
  unsigned short* Hloc = (unsigned short*)(ws + F_HLOC);
  float* Spre          = ws + F_SPRE;
  float* Hsup          = ws + F_HSUP;
  float* Ssup          = ws + F_SSUP;
  unsigned short* wbuf = (unsigned short*)(ws + F_WBUF);
  unsigned short* ipw  = wbuf;
  unsigned short* xpw  = wbuf + 147456;
  unsigned short* opw  = wbuf + 165888;

  hipLaunchKernelGGL(k_ln, dim3(1960), dim3(256), 0, stream, x, norm_w, norm_b, seqn,
                     in_proj_w, x_proj_w, out_proj_w, wbuf);
  hipLaunchKernelGGL(k_inproj, dim3(128, 6), dim3(256), 0, stream, seqn, ipw, xin, z);
  hipLaunchKernelGGL(k_convx, dim3(128, 4), dim3(384), 0, stream, xin, conv_w, conv_b, xpw,
                     dt_proj_w, dt_proj_b, A_log, xsb, dbl, dtb, Hloc, Sbuf);
  hipLaunchKernelGGL(k_scanB1, dim3(512), dim3(384), 0, stream, A_log, Hloc, Sbuf, Spre, Hsup,
                     Ssup);
  hipLaunchKernelGGL(k_scanC, dim3(512), dim3(384), 0, stream, xsb, dtb, dbl, z, A_log, Dw,
                     Hloc, Spre, Hsup, Ssup, opw, x, out);
}

// Round 15
// 96.428 us; speedup vs baseline: 1.0774x; 1.0011x over previous
//
#include <hip/hip_runtime.h>
#include <hip/hip_bf16.h>
#include <hip/hip_cooperative_groups.h>

// Problem constants
constexpr int B_ = 4;
constexpr int C_ = 192;
constexpr int L_ = 4096;     // H*W
constexpr int DI = 384;      // d_inner
constexpr int DSs = 16;      // d_state
constexpr int DTR = 12;      // dt_rank
constexpr int NDBL = 44;     // dt_rank + 2*d_state
constexpr int NCHUNK = 128;  // scan chunks
constexpr int CSZ = 32;      // chunk size
constexpr int NSUP = 8;      // super-chunks (16 chunks each)

constexpr size_t BL = (size_t)B_ * L_;  // 16384

// Workspace offsets in FLOAT units (bf16 counted at half)
constexpr size_t F_SEQN = 0;                                   // bf16 BL*C
constexpr size_t F_XIN  = F_SEQN + BL * C_ / 2;                // bf16 BL*DI
constexpr size_t F_Z    = F_XIN + BL * DI / 2;                 // bf16 BL*DI
constexpr size_t F_XSB  = F_Z + BL * DI / 2;                   // bf16 BL*DI (fallback only)
constexpr size_t F_DBL  = F_XSB + BL * DI / 2;                 // f32  BL*NDBL (fallback only)
constexpr size_t F_DT   = F_DBL + BL * NDBL;                   // bf16 BL*DI (fallback only)
constexpr size_t F_SBUF = F_DT + BL * DI / 2;                  // f32  B*NCHUNK*DI
constexpr size_t F_HLOC = F_SBUF + (size_t)B_ * NCHUNK * DI;   // bf16 B*NCHUNK*16*DI
constexpr size_t F_SPRE = F_HLOC + (size_t)B_ * NCHUNK * DI * 16 / 2;  // f32 B*NCHUNK*DI
constexpr size_t F_HSUP = F_SPRE + (size_t)B_ * NCHUNK * DI;   // f32 B*NSUP*16*DI
constexpr size_t F_SSUP = F_HSUP + (size_t)B_ * NSUP * 16 * DI;// f32 B*NSUP*DI
constexpr size_t F_WBUF = F_SSUP + (size_t)B_ * NSUP * DI;     // bf16 weights
// total ~= 70 MB (prior rounds used 129 MB: safe)

typedef __attribute__((ext_vector_type(8))) short bf16x8;
typedef __attribute__((ext_vector_type(4))) float f32x4;

__device__ __forceinline__ unsigned short f2bf(float v) {
  unsigned x = __builtin_bit_cast(unsigned, v);
  unsigned r = x + 0x7FFFu + ((x >> 16) & 1u);   // RNE
  return (unsigned short)(r >> 16);
}
__device__ __forceinline__ float bf2f(unsigned short u) {
  return __builtin_bit_cast(float, (unsigned)u << 16);
}
__device__ __forceinline__ void gload16(const void* g, void* l) {
  __builtin_amdgcn_global_load_lds((const __attribute__((address_space(1))) void*)g,
                                   (__attribute__((address_space(3))) void*)l, 16, 0, 0);
}
#define MFMA16(a, b, c) __builtin_amdgcn_mfma_f32_16x16x32_bf16(a, b, c, 0, 0, 0)

// ---------------- LayerNorm (blocks 0..1023, 16-row tiles) + weight cvt tail ---------
__global__ __launch_bounds__(256) void k_ln(const float* __restrict__ x,
                                            const float* __restrict__ nw,
                                            const float* __restrict__ nb,
                                            unsigned short* __restrict__ seqn,
                                            const float* __restrict__ ipw,
                                            const float* __restrict__ xpw,
                                            const float* __restrict__ opw,
                                            unsigned short* __restrict__ wbuf) {
  if (blockIdx.x >= 1024) {
    int t = (blockIdx.x - 1024) * 256 + threadIdx.x;
    if (t < 239616) {
      float v;
      if (t < 147456) v = ipw[t];
      else if (t < 165888) {
        int j = t - 147456;
        int r = j / 384, c = j - r * 384;
        v = (r < 44) ? xpw[r * 384 + c] : 0.f;
      } else v = opw[t - 165888];
      wbuf[t] = f2bf(v);
    }
    return;
  }
  __shared__ unsigned short xt[192][18];
  __shared__ float ps[16][16], ps2[16][16];
  __shared__ float mu_[16], rs_[16];
  __shared__ float wsh[192], bsh[192];
  int tid = threadIdx.x;
  int blk = blockIdx.x;          // 0..1023
  int b = blk >> 8;
  int l0 = (blk & 255) << 4;
  const float* xb = x + (size_t)b * C_ * L_;
  for (int idx = tid; idx < 192 * 4; idx += 256) {
    int c = idx >> 2, lq = idx & 3;
    float4 v = *(const float4*)&xb[(size_t)c * L_ + l0 + (lq << 2)];
    ushort2 u0, u1;
    u0.x = f2bf(v.x); u0.y = f2bf(v.y);
    u1.x = f2bf(v.z); u1.y = f2bf(v.w);
    *(ushort2*)&xt[c][(lq << 2)] = u0;
    *(ushort2*)&xt[c][(lq << 2) + 2] = u1;
  }
  if (tid < 192) { wsh[tid] = nw[tid]; bsh[tid] = nb[tid]; }
  __syncthreads();
  int ll = tid & 15, q = tid >> 4;   // 16 groups x 12 channels
  float s = 0.f, ss = 0.f;
  for (int c = q * 12; c < q * 12 + 12; ++c) {
    float v = bf2f(xt[c][ll]);
    s += v; ss += v * v;
  }
  ps[q][ll] = s; ps2[q][ll] = ss;
  __syncthreads();
  if (q == 0) {
    float st = 0.f, sst = 0.f;
#pragma unroll
    for (int g = 0; g < 16; ++g) { st += ps[g][ll]; sst += ps2[g][ll]; }
    float mu = st * (1.f / 192.f);
    float var = sst * (1.f / 192.f) - mu * mu;
    mu_[ll] = mu; rs_[ll] = rsqrtf(var + 1e-5f);
  }
  __syncthreads();
  unsigned short* so = seqn + ((size_t)b * L_ + l0) * C_;
  for (int idx = tid; idx < 16 * 192; idx += 256) {
    int l = idx / 192, c = idx - l * 192;
    so[idx] = f2bf((bf2f(xt[c][l]) - mu_[l]) * rs_[l] * wsh[c] + bsh[c]);
  }
}

// ---------------- in_proj MFMA: seqn(BL,192)bf16 @ W(768,192)^T -> xin,z bf16 --------
__global__ __launch_bounds__(256) void k_inproj(const unsigned short* __restrict__ A,
                                                const unsigned short* __restrict__ W,
                                                unsigned short* __restrict__ xin,
                                                unsigned short* __restrict__ z) {
  __shared__ unsigned short smem[16384];
  unsigned short* As = smem;
  unsigned short* Bs = smem + 8192;
  int tid = threadIdx.x;
  int w = tid >> 6, l = tid & 63;
  int wr = w >> 1, wc = w & 1;
  int m0 = blockIdx.x << 7;
  int n0 = blockIdx.y << 7;
  f32x4 acc[4][4];
#pragma unroll
  for (int i = 0; i < 4; ++i)
#pragma unroll
    for (int j = 0; j < 4; ++j) acc[i][j] = (f32x4){0.f, 0.f, 0.f, 0.f};
  int lr = l & 15, lk = l >> 4;
  for (int kt = 0; kt < 3; ++kt) {
    int k0 = kt * 64;
    if (kt) __syncthreads();
#pragma unroll
    for (int i = 0; i < 4; ++i) {
      int row = (i << 5) + (tid >> 3);
      int gc = k0 + (((tid & 7) ^ (row & 7)) << 3);
      gload16(A + (size_t)(m0 + row) * 192 + gc, &As[(i << 11) + (w << 9)]);
      gload16(W + (size_t)(n0 + row) * 192 + gc, &Bs[(i << 11) + (w << 9)]);
    }
    __syncthreads();
#pragma unroll
    for (int ks = 0; ks < 2; ++ks) {
      int s = (ks << 2) + lk;
      bf16x8 af[4], bfr[4];
#pragma unroll
      for (int mi = 0; mi < 4; ++mi) {
        int r = (wr << 6) + (mi << 4) + lr;
        af[mi] = *(const bf16x8*)&As[r * 64 + ((s ^ (r & 7)) << 3)];
      }
#pragma unroll
      for (int ni = 0; ni < 4; ++ni) {
        int r = (wc << 6) + (ni << 4) + lr;
        bfr[ni] = *(const bf16x8*)&Bs[r * 64 + ((s ^ (r & 7)) << 3)];
      }
#pragma unroll
      for (int mi = 0; mi < 4; ++mi)
#pragma unroll
        for (int ni = 0; ni < 4; ++ni) acc[mi][ni] = MFMA16(af[mi], bfr[ni], acc[mi][ni]);
    }
  }
  __syncthreads();
#pragma unroll
  for (int mi = 0; mi < 4; ++mi)
#pragma unroll
    for (int ni = 0; ni < 4; ++ni) {
      int col = (wc << 6) + (ni << 4) + lr;
#pragma unroll
      for (int r = 0; r < 4; ++r) {
        int row = (wr << 6) + (mi << 4) + (lk << 2) + r;
        smem[(row << 7) + col] = f2bf(acc[mi][ni][r]);
      }
    }
  __syncthreads();
#pragma unroll
  for (int i = 0; i < 8; ++i) {
    int chunk = i * 256 + tid;
    int row = chunk >> 4, cq = chunk & 15;
    int n = n0 + (cq << 3);
    unsigned short* dst = (n < 384) ? (xin + (size_t)(m0 + row) * DI + n)
                                    : (z + (size_t)(m0 + row) * DI + (n - 384));
    *(bf16x8*)dst = *(const bf16x8*)&smem[(row << 7) + (cq << 3)];
  }
}

// ======================= FALLBACK PATH (round-13, proven 96.5 µs) ====================
__global__ __launch_bounds__(384) void k_convx(const unsigned short* __restrict__ xin,
                                               const float* __restrict__ cw,
                                               const float* __restrict__ cb,
                                               const unsigned short* __restrict__ W,
                                               const float* __restrict__ dw,
                                               const float* __restrict__ dbias,
                                               const float* __restrict__ A_log,
                                               unsigned short* __restrict__ xsb,
                                               float* __restrict__ dbl,
                                               unsigned short* __restrict__ dtb,
                                               unsigned short* __restrict__ Hloc,
                                               float* __restrict__ Sbuf) {
  __shared__ unsigned short xs[6 * 2048];
  __shared__ unsigned short Bs[2][3072];
  __shared__ float dl[CSZ][12];
  __shared__ float Bsh2[CSZ][16];
  int tid = threadIdx.x;
  int w = tid >> 6, l = tid & 63;
  int b = blockIdx.y;
  int chunk = blockIdx.x;
  int l0 = chunk << 5;
  int d = tid;
  float4 w4 = *(const float4*)&cw[d * 4];
  float bb = cb[d];
  const unsigned short* xp = xin + ((size_t)b * L_ + l0) * DI + d;
  unsigned short* op = xsb + ((size_t)b * L_ + l0) * DI + d;
  float x0 = 0.f, x1 = 0.f, x2 = 0.f;
  if (l0 > 0) {
    x0 = bf2f(*(xp - 3 * DI));
    x1 = bf2f(*(xp - 2 * DI));
    x2 = bf2f(*(xp - DI));
  }
  int kt = d >> 6, col = d & 63, g = col >> 3, e = col & 7;
  unsigned short* xsrow = xs + kt * 2048;
  for (int r = 0; r < 32; ++r) {
    float xv = bf2f(xp[(size_t)r * DI]);
    float a = bb + w4.x * x0 + w4.y * x1 + w4.z * x2 + w4.w * xv;
    float sv = a * __builtin_amdgcn_rcpf(1.f + __expf(-a));
    unsigned short sb = f2bf(sv);
    xsrow[r * 64 + ((g ^ (r & 7)) << 3) + e] = sb;
    op[(size_t)r * DI] = sb;
    x0 = x1; x1 = x2; x2 = xv;
  }
  __syncthreads();
  int lr = l & 15, lk = l >> 4;
  int mt = w & 1, nt = w >> 1;
  {
    int row = tid >> 3;
    int gc = (((tid & 7) ^ (row & 7)) << 3);
    gload16(W + (size_t)row * 384 + gc, &Bs[0][w << 9]);
  }
  f32x4 accx = (f32x4){0.f, 0.f, 0.f, 0.f};
  for (int kt2 = 0; kt2 < 6; ++kt2) {
    __syncthreads();
    if (kt2 < 5) {
      int k0 = (kt2 + 1) * 64;
      int row = tid >> 3;
      int gc = k0 + (((tid & 7) ^ (row & 7)) << 3);
      gload16(W + (size_t)row * 384 + gc, &Bs[(kt2 + 1) & 1][w << 9]);
    }
    const unsigned short* Bcur = Bs[kt2 & 1];
#pragma unroll
    for (int ks = 0; ks < 2; ++ks) {
      int s = (ks << 2) + lk;
      int ar = (mt << 4) + lr;
      bf16x8 a = *(const bf16x8*)&xs[kt2 * 2048 + ar * 64 + ((s ^ (ar & 7)) << 3)];
      int br = (nt << 4) + lr;
      bf16x8 bbv = *(const bf16x8*)&Bcur[br * 64 + ((s ^ (br & 7)) << 3)];
      accx = MFMA16(a, bbv, accx);
    }
  }
  {
    int colq = (nt << 4) + lr;
#pragma unroll
    for (int r = 0; r < 4; ++r) {
      int row = (mt << 4) + (lk << 2) + r;
      float v = accx[r];
      if (colq < NDBL) dbl[((size_t)b * L_ + l0 + row) * NDBL + colq] = v;
      if (colq < 12) dl[row][colq] = v;
      else if (colq < 28) Bsh2[row][colq - 12] = v;
    }
  }
  __syncthreads();
  float4 wv0 = *(const float4*)&dw[d * 12];
  float4 wv1 = *(const float4*)&dw[d * 12 + 4];
  float4 wv2 = *(const float4*)&dw[d * 12 + 8];
  float bias = dbias[d];
  bool fast = true;
#pragma unroll
  for (int n = 0; n < 16; ++n) {
    float An_ = -__expf(A_log[d * 16 + n]);
    fast = fast && (fabsf(An_ + (float)(n + 1)) < 2e-3f);
  }
  unsigned short* dtp = dtb + ((size_t)b * L_ + l0) * DI + d;
  float h[16];
#pragma unroll
  for (int n = 0; n < 16; ++n) h[n] = 0.f;
  float S = 0.f;
  if (fast) {
#pragma unroll
    for (int i = 0; i < CSZ; ++i) {
      float4 c0 = *(const float4*)&dl[i][0];
      float4 c1 = *(const float4*)&dl[i][4];
      float4 c2 = *(const float4*)&dl[i][8];
      float a = bias;
      a = fmaf(wv0.x, c0.x, a); a = fmaf(wv0.y, c0.y, a);
      a = fmaf(wv0.z, c0.z, a); a = fmaf(wv0.w, c0.w, a);
      a = fmaf(wv1.x, c1.x, a); a = fmaf(wv1.y, c1.y, a);
      a = fmaf(wv1.z, c1.z, a); a = fmaf(wv1.w, c1.w, a);
      a = fmaf(wv2.x, c2.x, a); a = fmaf(wv2.y, c2.y, a);
      a = fmaf(wv2.z, c2.z, a); a = fmaf(wv2.w, c2.w, a);
      float sp = fmaxf(a, 0.f) + __logf(1.f + __expf(-fabsf(a)));
      dtp[(size_t)i * DI] = f2bf(sp);
      S += sp;
      float xv = bf2f(xsrow[i * 64 + ((g ^ (i & 7)) << 3) + e]);
      float dtx = sp * xv;
      float r = __expf(-sp);
      float r2 = r * r;
      float r4 = r2 * r2;
      float dA0 = r, dA1 = r2, dA2 = r2 * r, dA3 = r4;
#pragma unroll
      for (int gg = 0; gg < 4; ++gg) {
        float4 Bg = *(const float4*)&Bsh2[i][gg << 2];
        h[(gg << 2) + 0] = fmaf(dA0, h[(gg << 2) + 0], dtx * Bg.x);
        h[(gg << 2) + 1] = fmaf(dA1, h[(gg << 2) + 1], dtx * Bg.y);
        h[(gg << 2) + 2] = fmaf(dA2, h[(gg << 2) + 2], dtx * Bg.z);
        h[(gg << 2) + 3] = fmaf(dA3, h[(gg << 2) + 3], dtx * Bg.w);
        if (gg < 3) { dA0 *= r4; dA1 *= r4; dA2 *= r4; dA3 *= r4; }
      }
    }
  } else {
    float An[16];
#pragma unroll
    for (int n = 0; n < 16; ++n) An[n] = -__expf(A_log[d * 16 + n]);
#pragma unroll
    for (int i = 0; i < CSZ; ++i) {
      float4 c0 = *(const float4*)&dl[i][0];
      float4 c1 = *(const float4*)&dl[i][4];
      float4 c2 = *(const float4*)&dl[i][8];
      float a = bias;
      a = fmaf(wv0.x, c0.x, a); a = fmaf(wv0.y, c0.y, a);
      a = fmaf(wv0.z, c0.z, a); a = fmaf(wv0.w, c0.w, a);
      a = fmaf(wv1.x, c1.x, a); a = fmaf(wv1.y, c1.y, a);
      a = fmaf(wv1.z, c1.z, a); a = fmaf(wv1.w, c1.w, a);
      a = fmaf(wv2.x, c2.x, a); a = fmaf(wv2.y, c2.y, a);
      a = fmaf(wv2.z, c2.z, a); a = fmaf(wv2.w, c2.w, a);
      float sp = fmaxf(a, 0.f) + __logf(1.f + __expf(-fabsf(a)));
      dtp[(size_t)i * DI] = f2bf(sp);
      S += sp;
      float xv = bf2f(xsrow[i * 64 + ((g ^ (i & 7)) << 3) + e]);
      float dtx = sp * xv;
#pragma unroll
      for (int n = 0; n < 16; ++n)
        h[n] = fmaf(__expf(sp * An[n]), h[n], dtx * Bsh2[i][n]);
    }
  }
  size_t hbase = ((size_t)(b * NCHUNK + chunk) * 16) * DI + d;
#pragma unroll
  for (int n = 0; n < 16; ++n) Hloc[hbase + (size_t)n * DI] = f2bf(h[n]);
  Sbuf[((size_t)b * NCHUNK + chunk) * DI + d] = S;
}

__global__ __launch_bounds__(384) void k_scanB1(const float* __restrict__ A_log,
                                                unsigned short* __restrict__ Hloc,
                                                const float* __restrict__ Sbuf,
                                                float* __restrict__ Spre,
                                                float* __restrict__ Hsup,
                                                float* __restrict__ Ssup) {
  int d = threadIdx.x;
  int blk = blockIdx.x;
  int n = blk & 15;
  int s = (blk >> 4) & 7;
  int b = blk >> 7;
  float An = -__expf(A_log[d * 16 + n]);
  float h = 0.f, Sp = 0.f;
  int c0 = s * 16;
#pragma unroll
  for (int i = 0; i < 16; ++i) {
    int c = c0 + i;
    size_t hidx = (((size_t)(b * NCHUNK + c) * 16) + n) * DI + d;
    float Hl = bf2f(Hloc[hidx]);
    float S = Sbuf[((size_t)b * NCHUNK + c) * DI + d];
    Hloc[hidx] = f2bf(h);
    if (n == 0) Spre[((size_t)b * NCHUNK + c) * DI + d] = Sp;
    h = fmaf(__expf(An * S), h, Hl);
    Sp += S;
  }
  Hsup[(((size_t)(b * NSUP + s) * 16) + n) * DI + d] = h;
  if (n == 0) Ssup[((size_t)b * NSUP + s) * DI + d] = Sp;
}

__global__ __launch_bounds__(384) void k_scanC(const unsigned short* __restrict__ xsb,
                                               const unsigned short* __restrict__ dtb,
                                               const float* __restrict__ dbl,
                                               const unsigned short* __restrict__ z,
                                               const float* __restrict__ A_log,
                                               const float* __restrict__ Dw,
                                               const unsigned short* __restrict__ Hloc,
                                               const float* __restrict__ Spre,
                                               const float* __restrict__ Hsup,
                                               const float* __restrict__ Ssup,
                                               const unsigned short* __restrict__ Wo,
                                               const float* __restrict__ x,
                                               float* __restrict__ out) {
  __shared__ float BCsh[CSZ][32];
  __shared__ unsigned short yt[6 * 2048];
  __shared__ unsigned short Bs[12288];
  int tid = threadIdx.x;
  int blk = blockIdx.x;
  int b = blk >> 7;
  int chunk = blk & (NCHUNK - 1);
  int l0 = chunk << 5;
  int w = tid >> 6, l = tid & 63;
#pragma unroll
  for (int j = 0; j < 4; ++j) {
    int row = j * 48 + (tid >> 3);
    int gc = (((tid & 7) ^ (row & 7)) << 3);
    gload16(Wo + (size_t)row * 384 + gc, &Bs[j * 3072 + (w << 9)]);
  }
  for (int idx = tid; idx < CSZ * 32; idx += 384) {
    int r = idx >> 5, n32 = idx & 31;
    BCsh[r][n32] = dbl[((size_t)b * L_ + l0 + r) * NDBL + DTR + n32];
  }
  int d = tid;
  float Dd = Dw[d];
  bool fast = true;
#pragma unroll
  for (int n = 0; n < 16; ++n) {
    float An_ = -__expf(A_log[d * 16 + n]);
    fast = fast && (fabsf(An_ + (float)(n + 1)) < 2e-3f);
  }
  int sup = chunk >> 4;
  size_t hbase = ((size_t)(b * NCHUNK + chunk) * 16) * DI + d;
  float Spv = Spre[((size_t)b * NCHUNK + chunk) * DI + d];
  float h[16];
  if (fast) {
    float I[16];
#pragma unroll
    for (int n = 0; n < 16; ++n) I[n] = 0.f;
    for (int s = 0; s < sup; ++s) {
      float Ss = Ssup[((size_t)b * NSUP + s) * DI + d];
      const float* Hs = Hsup + ((size_t)(b * NSUP + s) * 16) * DI + d;
      float t = __expf(-Ss);
      float t2 = t * t, t4 = t2 * t2;
      float p0 = t, p1 = t2, p2 = t2 * t, p3 = t4;
#pragma unroll
      for (int gI = 0; gI < 4; ++gI) {
        I[(gI << 2) + 0] = fmaf(p0, I[(gI << 2) + 0], Hs[(size_t)((gI << 2) + 0) * DI]);
        I[(gI << 2) + 1] = fmaf(p1, I[(gI << 2) + 1], Hs[(size_t)((gI << 2) + 1) * DI]);
        I[(gI << 2) + 2] = fmaf(p2, I[(gI << 2) + 2], Hs[(size_t)((gI << 2) + 2) * DI]);
        I[(gI << 2) + 3] = fmaf(p3, I[(gI << 2) + 3], Hs[(size_t)((gI << 2) + 3) * DI]);
        if (gI < 3) { p0 *= t4; p1 *= t4; p2 *= t4; p3 *= t4; }
      }
    }
    float t = __expf(-Spv);
    float t2 = t * t, t4 = t2 * t2;
    float p0 = t, p1 = t2, p2 = t2 * t, p3 = t4;
#pragma unroll
    for (int gI = 0; gI < 4; ++gI) {
      h[(gI << 2) + 0] = fmaf(p0, I[(gI << 2) + 0], bf2f(Hloc[hbase + (size_t)((gI << 2) + 0) * DI]));
      h[(gI << 2) + 1] = fmaf(p1, I[(gI << 2) + 1], bf2f(Hloc[hbase + (size_t)((gI << 2) + 1) * DI]));
      h[(gI << 2) + 2] = fmaf(p2, I[(gI << 2) + 2], bf2f(Hloc[hbase + (size_t)((gI << 2) + 2) * DI]));
      h[(gI << 2) + 3] = fmaf(p3, I[(gI << 2) + 3], bf2f(Hloc[hbase + (size_t)((gI << 2) + 3) * DI]));
      if (gI < 3) { p0 *= t4; p1 *= t4; p2 *= t4; p3 *= t4; }
    }
  } else {
    float An[16];
#pragma unroll
    for (int n = 0; n < 16; ++n) An[n] = -__expf(A_log[d * 16 + n]);
    float I[16];
#pragma unroll
    for (int n = 0; n < 16; ++n) I[n] = 0.f;
    for (int s = 0; s < sup; ++s) {
      float Ss = Ssup[((size_t)b * NSUP + s) * DI + d];
      const float* Hs = Hsup + ((size_t)(b * NSUP + s) * 16) * DI + d;
#pragma unroll
      for (int n = 0; n < 16; ++n)
        I[n] = fmaf(__expf(An[n] * Ss), I[n], Hs[(size_t)n * DI]);
    }
#pragma unroll
    for (int n = 0; n < 16; ++n)
      h[n] = fmaf(__expf(An[n] * Spv), I[n], bf2f(Hloc[hbase + (size_t)n * DI]));
  }
  const unsigned short* xp = xsb + ((size_t)b * L_ + l0) * DI + d;
  const unsigned short* dtp = dtb + ((size_t)b * L_ + l0) * DI + d;
  const unsigned short* zp = z + ((size_t)b * L_ + l0) * DI + d;
  int ktile = d >> 6, colq = d & 63, gq = colq >> 3, eq = colq & 7;
  unsigned short* ytp = yt + ktile * 2048;
  __syncthreads();
  if (fast) {
#pragma unroll
    for (int i = 0; i < CSZ; ++i) {
      float sp = bf2f(dtp[(size_t)i * DI]);
      float xv = bf2f(xp[(size_t)i * DI]);
      float zv = bf2f(zp[(size_t)i * DI]);
      float dtx = sp * xv;
      float r = __expf(-sp);
      float r2 = r * r;
      float r4 = r2 * r2;
      float dA0 = r, dA1 = r2, dA2 = r2 * r, dA3 = r4;
      float y = 0.f;
#pragma unroll
      for (int g = 0; g < 4; ++g) {
        float4 Bg = *(const float4*)&BCsh[i][g << 2];
        float4 Cg = *(const float4*)&BCsh[i][16 + (g << 2)];
        h[(g << 2) + 0] = fmaf(dA0, h[(g << 2) + 0], dtx * Bg.x);
        h[(g << 2) + 1] = fmaf(dA1, h[(g << 2) + 1], dtx * Bg.y);
        h[(g << 2) + 2] = fmaf(dA2, h[(g << 2) + 2], dtx * Bg.z);
        h[(g << 2) + 3] = fmaf(dA3, h[(g << 2) + 3], dtx * Bg.w);
        y = fmaf(h[(g << 2) + 0], Cg.x, y);
        y = fmaf(h[(g << 2) + 1], Cg.y, y);
        y = fmaf(h[(g << 2) + 2], Cg.z, y);
        y = fmaf(h[(g << 2) + 3], Cg.w, y);
        if (g < 3) { dA0 *= r4; dA1 *= r4; dA2 *= r4; dA3 *= r4; }
      }
      y = fmaf(xv, Dd, y);
      float sig = __builtin_amdgcn_rcpf(1.f + __expf(-zv));
      ytp[i * 64 + ((gq ^ (i & 7)) << 3) + eq] = f2bf(y * (zv * sig));
    }
  } else {
    float An[16];
#pragma unroll
    for (int n = 0; n < 16; ++n) An[n] = -__expf(A_log[d * 16 + n]);
#pragma unroll
    for (int i = 0; i < CSZ; ++i) {
      float sp = bf2f(dtp[(size_t)i * DI]);
      float xv = bf2f(xp[(size_t)i * DI]);
      float zv = bf2f(zp[(size_t)i * DI]);
      float dtx = sp * xv;
      float y = 0.f;
#pragma unroll
      for (int n = 0; n < 16; ++n) {
        h[n] = fmaf(__expf(sp * An[n]), h[n], dtx * BCsh[i][n]);
        y = fmaf(h[n], BCsh[i][16 + n], y);
      }
      y = fmaf(xv, Dd, y);
      float sig = __builtin_amdgcn_rcpf(1.f + __expf(-zv));
      ytp[i * 64 + ((gq ^ (i & 7)) << 3) + eq] = f2bf(y * (zv * sig));
    }
  }
  int lr = l & 15, lk = l >> 4;
  int mt = w & 1;
  int ng = w >> 1;
  f32x4 acc[4];
#pragma unroll
  for (int j = 0; j < 4; ++j) acc[j] = (f32x4){0.f, 0.f, 0.f, 0.f};
  for (int kt = 0; kt < 6; ++kt) {
    __syncthreads();
#pragma unroll
    for (int ks = 0; ks < 2; ++ks) {
      int s = (ks << 2) + lk;
      bf16x8 a = *(const bf16x8*)&yt[kt * 2048 + (mt * 16 + lr) * 64 + ((s ^ (lr & 7)) << 3)];
#pragma unroll
      for (int j = 0; j < 4; ++j) {
        int br = (ng * 4 + j) * 16 + lr;
        bf16x8 bv = *(const bf16x8*)&Bs[br * 64 + ((s ^ (br & 7)) << 3)];
        acc[j] = MFMA16(a, bv, acc[j]);
      }
    }
    if (kt < 5) {
      __syncthreads();
      int k0 = (kt + 1) * 64;
#pragma unroll
      for (int j = 0; j < 4; ++j) {
        int row = j * 48 + (tid >> 3);
        int gc = k0 + (((tid & 7) ^ (row & 7)) << 3);
        gload16(Wo + (size_t)row * 384 + gc, &Bs[j * 3072 + (w << 9)]);
      }
    }
  }
#pragma unroll
  for (int j = 0; j < 4; ++j) {
    int c = (ng * 4 + j) * 16 + lr;
    size_t off = ((size_t)b * C_ + c) * L_ + l0 + mt * 16 + (lk << 2);
    f32x4 xv = *(const f32x4*)&x[off];
    *(f32x4*)&out[off] = acc[j] + xv;
  }
}

// ================= COOPERATIVE MEGA (VGPR-reduced: no xpk; x stays in LDS) ===========
__global__ __launch_bounds__(384) void k_mega(const unsigned short* __restrict__ xin,
                                              const float* __restrict__ cw,
                                              const float* __restrict__ cb,
                                              const unsigned short* __restrict__ W,
                                              const float* __restrict__ dw,
                                              const float* __restrict__ dbias,
                                              const float* __restrict__ A_log,
                                              const float* __restrict__ Dw,
                                              unsigned short* __restrict__ Hloc,
                                              float* __restrict__ Sbuf,
                                              float* __restrict__ Spre,
                                              float* __restrict__ Hsup,
                                              float* __restrict__ Ssup,
                                              const unsigned short* __restrict__ z,
                                              const unsigned short* __restrict__ Wo,
                                              const float* __restrict__ x,
                                              float* __restrict__ out) {
  __shared__ unsigned short xsyt[6 * 2048];   // conv-out tiles; phase C: overwritten by y
  __shared__ unsigned short BsW[12288];       // A: x_proj W dbuf (2x3072); C: Wo tile
  __shared__ float bc[CSZ][44];               // dbl (persists A -> C)
  namespace cg = cooperative_groups;
  cg::grid_group grid = cg::this_grid();
  int tid = threadIdx.x;
  int bid = blockIdx.x;       // 512
  int b = bid >> 7;
  int chunk = bid & 127;
  int l0 = chunk << 5;
  int d = tid;
  int w = tid >> 6, l = tid & 63;
  int lr = l & 15, lk = l >> 4;
  int ktA = d >> 6, colA = d & 63, g = colA >> 3, e = colA & 7;
  unsigned dtpk[16];   // packed bf16 dt pairs, persist across grid syncs

  // phase A1: conv + SiLU -> LDS only
  {
    float4 w4 = *(const float4*)&cw[d * 4];
    float bb = cb[d];
    const unsigned short* xp = xin + ((size_t)b * L_ + l0) * DI + d;
    float x0 = 0.f, x1 = 0.f, x2 = 0.f;
    if (l0 > 0) {
      x0 = bf2f(*(xp - 3 * DI));
      x1 = bf2f(*(xp - 2 * DI));
      x2 = bf2f(*(xp - DI));
    }
    unsigned short* xsrow = xsyt + ktA * 2048;
#pragma unroll
    for (int r = 0; r < 32; ++r) {
      float xv = bf2f(xp[(size_t)r * DI]);
      float a = bb + w4.x * x0 + w4.y * x1 + w4.z * x2 + w4.w * xv;
      float sv = a * __builtin_amdgcn_rcpf(1.f + __expf(-a));
      xsrow[r * 64 + ((g ^ (r & 7)) << 3) + e] = f2bf(sv);
      x0 = x1; x1 = x2; x2 = xv;
    }
  }
  __syncthreads();
  // phase A2: x_proj MFMA (6-wave, dbuf W)
  int mt = w & 1, nt = w >> 1;
  {
    int row = tid >> 3;
    int gc = (((tid & 7) ^ (row & 7)) << 3);
    gload16(W + (size_t)row * 384 + gc, &BsW[w << 9]);
  }
  f32x4 accx = (f32x4){0.f, 0.f, 0.f, 0.f};
  for (int kt2 = 0; kt2 < 6; ++kt2) {
    __syncthreads();
    if (kt2 < 5) {
      int k0 = (kt2 + 1) * 64;
      int row = tid >> 3;
      int gc = k0 + (((tid & 7) ^ (row & 7)) << 3);
      gload16(W + (size_t)row * 384 + gc, &BsW[((kt2 + 1) & 1) * 3072 + (w << 9)]);
    }
    const unsigned short* Bcur = BsW + (kt2 & 1) * 3072;
#pragma unroll
    for (int ks = 0; ks < 2; ++ks) {
      int s = (ks << 2) + lk;
      int ar = (mt << 4) + lr;
      bf16x8 a = *(const bf16x8*)&xsyt[kt2 * 2048 + ar * 64 + ((s ^ (ar & 7)) << 3)];
      int br = (nt << 4) + lr;
      bf16x8 bbv = *(const bf16x8*)&Bcur[br * 64 + ((s ^ (br & 7)) << 3)];
      accx = MFMA16(a, bbv, accx);
    }
  }
  // phase A3: dbl -> LDS bc
  {
    int colq = (nt << 4) + lr;
#pragma unroll
    for (int r = 0; r < 4; ++r) {
      int row = (mt << 4) + (lk << 2) + r;
      if (colq < NDBL) bc[row][colq] = accx[r];
    }
  }
  __syncthreads();
  // phase A4: dt_proj + chunk-local scan (x from LDS)
  bool fast = true;
#pragma unroll
  for (int n = 0; n < 16; ++n) {
    float An_ = -__expf(A_log[d * 16 + n]);
    fast = fast && (fabsf(An_ + (float)(n + 1)) < 2e-3f);
  }
  float h[16];
#pragma unroll
  for (int n = 0; n < 16; ++n) h[n] = 0.f;
  {
    float4 wv0 = *(const float4*)&dw[d * 12];
    float4 wv1 = *(const float4*)&dw[d * 12 + 4];
    float4 wv2 = *(const float4*)&dw[d * 12 + 8];
    float bias = dbias[d];
    const unsigned short* xsrow = xsyt + ktA * 2048;
    float S = 0.f;
    if (fast) {
#pragma unroll
      for (int i = 0; i < CSZ; ++i) {
        float4 c0 = *(const float4*)&bc[i][0];
        float4 c1 = *(const float4*)&bc[i][4];
        float4 c2 = *(const float4*)&bc[i][8];
        float a = bias;
        a = fmaf(wv0.x, c0.x, a); a = fmaf(wv0.y, c0.y, a);
        a = fmaf(wv0.z, c0.z, a); a = fmaf(wv0.w, c0.w, a);
        a = fmaf(wv1.x, c1.x, a); a = fmaf(wv1.y, c1.y, a);
        a = fmaf(wv1.z, c1.z, a); a = fmaf(wv1.w, c1.w, a);
        a = fmaf(wv2.x, c2.x, a); a = fmaf(wv2.y, c2.y, a);
        a = fmaf(wv2.z, c2.z, a); a = fmaf(wv2.w, c2.w, a);
        float sp = fmaxf(a, 0.f) + __logf(1.f + __expf(-fabsf(a)));
        unsigned short su = f2bf(sp);
        if ((i & 1) == 0) dtpk[i >> 1] = (unsigned)su;
        else dtpk[i >> 1] |= ((unsigned)su) << 16;
        S += sp;
        float xv = bf2f(xsrow[i * 64 + ((g ^ (i & 7)) << 3) + e]);
        float dtx = sp * xv;
        float r = __expf(-sp);
        float r2 = r * r;
        float r4 = r2 * r2;
        float dA0 = r, dA1 = r2, dA2 = r2 * r, dA3 = r4;
#pragma unroll
        for (int gg = 0; gg < 4; ++gg) {
          float4 Bg = *(const float4*)&bc[i][12 + (gg << 2)];
          h[(gg << 2) + 0] = fmaf(dA0, h[(gg << 2) + 0], dtx * Bg.x);
          h[(gg << 2) + 1] = fmaf(dA1, h[(gg << 2) + 1], dtx * Bg.y);
          h[(gg << 2) + 2] = fmaf(dA2, h[(gg << 2) + 2], dtx * Bg.z);
          h[(gg << 2) + 3] = fmaf(dA3, h[(gg << 2) + 3], dtx * Bg.w);
          if (gg < 3) { dA0 *= r4; dA1 *= r4; dA2 *= r4; dA3 *= r4; }
        }
      }
    } else {
      float An[16];
#pragma unroll
      for (int n = 0; n < 16; ++n) An[n] = -__expf(A_log[d * 16 + n]);
#pragma unroll
      for (int i = 0; i < CSZ; ++i) {
        float4 c0 = *(const float4*)&bc[i][0];
        float4 c1 = *(const float4*)&bc[i][4];
        float4 c2 = *(const float4*)&bc[i][8];
        float a = bias;
        a = fmaf(wv0.x, c0.x, a); a = fmaf(wv0.y, c0.y, a);
        a = fmaf(wv0.z, c0.z, a); a = fmaf(wv0.w, c0.w, a);
        a = fmaf(wv1.x, c1.x, a); a = fmaf(wv1.y, c1.y, a);
        a = fmaf(wv1.z, c1.z, a); a = fmaf(wv1.w, c1.w, a);
        a = fmaf(wv2.x, c2.x, a); a = fmaf(wv2.y, c2.y, a);
        a = fmaf(wv2.z, c2.z, a); a = fmaf(wv2.w, c2.w, a);
        float sp = fmaxf(a, 0.f) + __logf(1.f + __expf(-fabsf(a)));
        unsigned short su = f2bf(sp);
        if ((i & 1) == 0) dtpk[i >> 1] = (unsigned)su;
        else dtpk[i >> 1] |= ((unsigned)su) << 16;
        S += sp;
        float xv = bf2f(xsrow[i * 64 + ((g ^ (i & 7)) << 3) + e]);
        float dtx = sp * xv;
#pragma unroll
        for (int n = 0; n < 16; ++n)
          h[n] = fmaf(__expf(sp * An[n]), h[n], dtx * bc[i][12 + n]);
      }
    }
    size_t hbase = ((size_t)(b * NCHUNK + chunk) * 16) * DI + d;
#pragma unroll
    for (int n = 0; n < 16; ++n) Hloc[hbase + (size_t)n * DI] = f2bf(h[n]);
    Sbuf[((size_t)b * NCHUNK + chunk) * DI + d] = S;
  }
  grid.sync();
  // phase B1: per-super local prefix + super totals
  {
    int n2 = bid & 15;
    int s2 = (bid >> 4) & 7;
    int b2 = bid >> 7;
    float An = -__expf(A_log[d * 16 + n2]);
    float hh = 0.f, Sp = 0.f;
    int c0 = s2 * 16;
#pragma unroll
    for (int i = 0; i < 16; ++i) {
      int c = c0 + i;
      size_t hidx = (((size_t)(b2 * NCHUNK + c) * 16) + n2) * DI + d;
      float Hl = bf2f(Hloc[hidx]);
      float Sv = Sbuf[((size_t)b2 * NCHUNK + c) * DI + d];
      Hloc[hidx] = f2bf(hh);
      if (n2 == 0) Spre[((size_t)b2 * NCHUNK + c) * DI + d] = Sp;
      hh = fmaf(__expf(An * Sv), hh, Hl);
      Sp += Sv;
    }
    Hsup[(((size_t)(b2 * NSUP + s2) * 16) + n2) * DI + d] = hh;
    if (n2 == 0) Ssup[((size_t)b2 * NSUP + s2) * DI + d] = Sp;
  }
  grid.sync();
  // phase C: Wo prefetch + inline super-carry + scan replay + out_proj
#pragma unroll
  for (int j = 0; j < 4; ++j) {
    int row = j * 48 + (tid >> 3);
    int gc = (((tid & 7) ^ (row & 7)) << 3);
    gload16(Wo + (size_t)row * 384 + gc, &BsW[j * 3072 + (w << 9)]);
  }
  float Dd = Dw[d];
  int sup = chunk >> 4;
  size_t hbase = ((size_t)(b * NCHUNK + chunk) * 16) * DI + d;
  float Spv = Spre[((size_t)b * NCHUNK + chunk) * DI + d];
  if (fast) {
    float I[16];
#pragma unroll
    for (int n = 0; n < 16; ++n) I[n] = 0.f;
    for (int s = 0; s < sup; ++s) {
      float Ss = Ssup[((size_t)b * NSUP + s) * DI + d];
      const float* Hs = Hsup + ((size_t)(b * NSUP + s) * 16) * DI + d;
      float t = __expf(-Ss);
      float t2 = t * t, t4 = t2 * t2;
      float p0 = t, p1 = t2, p2 = t2 * t, p3 = t4;
#pragma unroll
      for (int gI = 0; gI < 4; ++gI) {
        I[(gI << 2) + 0] = fmaf(p0, I[(gI << 2) + 0], Hs[(size_t)((gI << 2) + 0) * DI]);
        I[(gI << 2) + 1] = fmaf(p1, I[(gI << 2) + 1], Hs[(size_t)((gI << 2) + 1) * DI]);
        I[(gI << 2) + 2] = fmaf(p2, I[(gI << 2) + 2], Hs[(size_t)((gI << 2) + 2) * DI]);
        I[(gI << 2) + 3] = fmaf(p3, I[(gI << 2) + 3], Hs[(size_t)((gI << 2) + 3) * DI]);
        if (gI < 3) { p0 *= t4; p1 *= t4; p2 *= t4; p3 *= t4; }
      }
    }
    float t = __expf(-Spv);
    float t2 = t * t, t4 = t2 * t2;
    float p0 = t, p1 = t2, p2 = t2 * t, p3 = t4;
#pragma unroll
    for (int gI = 0; gI < 4; ++gI) {
      h[(gI << 2) + 0] = fmaf(p0, I[(gI << 2) + 0], bf2f(Hloc[hbase + (size_t)((gI << 2) + 0) * DI]));
      h[(gI << 2) + 1] = fmaf(p1, I[(gI << 2) + 1], bf2f(Hloc[hbase + (size_t)((gI << 2) + 1) * DI]));
      h[(gI << 2) + 2] = fmaf(p2, I[(gI << 2) + 2], bf2f(Hloc[hbase + (size_t)((gI << 2) + 2) * DI]));
      h[(gI << 2) + 3] = fmaf(p3, I[(gI << 2) + 3], bf2f(Hloc[hbase + (size_t)((gI << 2) + 3) * DI]));
      if (gI < 3) { p0 *= t4; p1 *= t4; p2 *= t4; p3 *= t4; }
    }
  } else {
    float An[16];
#pragma unroll
    for (int n = 0; n < 16; ++n) An[n] = -__expf(A_log[d * 16 + n]);
    float I[16];
#pragma unroll
    for (int n = 0; n < 16; ++n) I[n] = 0.f;
    for (int s = 0; s < sup; ++s) {
      float Ss = Ssup[((size_t)b * NSUP + s) * DI + d];
      const float* Hs = Hsup + ((size_t)(b * NSUP + s) * 16) * DI + d;
#pragma unroll
      for (int n = 0; n < 16; ++n)
        I[n] = fmaf(__expf(An[n] * Ss), I[n], Hs[(size_t)n * DI]);
    }
#pragma unroll
    for (int n = 0; n < 16; ++n)
      h[n] = fmaf(__expf(An[n] * Spv), I[n], bf2f(Hloc[hbase + (size_t)n * DI]));
  }
  // scan replay: x read from LDS slot, then overwritten with y (same-thread slot)
  {
    const unsigned short* zp = z + ((size_t)b * L_ + l0) * DI + d;
    unsigned short* ytp = xsyt + ktA * 2048;
    if (fast) {
#pragma unroll
      for (int i = 0; i < CSZ; ++i) {
        unsigned short du = (i & 1) ? (unsigned short)(dtpk[i >> 1] >> 16)
                                    : (unsigned short)(dtpk[i >> 1] & 0xFFFFu);
        int slot = i * 64 + ((g ^ (i & 7)) << 3) + e;
        float sp = bf2f(du);
        float xv = bf2f(ytp[slot]);
        float zv = bf2f(zp[(size_t)i * DI]);
        float dtx = sp * xv;
        float r = __expf(-sp);
        float r2 = r * r;
        float r4 = r2 * r2;
        float dA0 = r, dA1 = r2, dA2 = r2 * r, dA3 = r4;
        float y = 0.f;
#pragma unroll
        for (int gg = 0; gg < 4; ++gg) {
          float4 Bg = *(const float4*)&bc[i][12 + (gg << 2)];
          float4 Cg = *(const float4*)&bc[i][28 + (gg << 2)];
          h[(gg << 2) + 0] = fmaf(dA0, h[(gg << 2) + 0], dtx * Bg.x);
          h[(gg << 2) + 1] = fmaf(dA1, h[(gg << 2) + 1], dtx * Bg.y);
          h[(gg << 2) + 2] = fmaf(dA2, h[(gg << 2) + 2], dtx * Bg.z);
          h[(gg << 2) + 3] = fmaf(dA3, h[(gg << 2) + 3], dtx * Bg.w);
          y = fmaf(h[(gg << 2) + 0], Cg.x, y);
          y = fmaf(h[(gg << 2) + 1], Cg.y, y);
          y = fmaf(h[(gg << 2) + 2], Cg.z, y);
          y = fmaf(h[(gg << 2) + 3], Cg.w, y);
          if (gg < 3) { dA0 *= r4; dA1 *= r4; dA2 *= r4; dA3 *= r4; }
        }
        y = fmaf(xv, Dd, y);
        float sig = __builtin_amdgcn_rcpf(1.f + __expf(-zv));
        ytp[slot] = f2bf(y * (zv * sig));
      }
    } else {
      float An[16];
#pragma unroll
      for (int n = 0; n < 16; ++n) An[n] = -__expf(A_log[d * 16 + n]);
#pragma unroll
      for (int i = 0; i < CSZ; ++i) {
        unsigned short du = (i & 1) ? (unsigned short)(dtpk[i >> 1] >> 16)
                                    : (unsigned short)(dtpk[i >> 1] & 0xFFFFu);
        int slot = i * 64 + ((g ^ (i & 7)) << 3) + e;
        float sp = bf2f(du);
        float xv = bf2f(ytp[slot]);
        float zv = bf2f(zp[(size_t)i * DI]);
        float dtx = sp * xv;
        float y = 0.f;
#pragma unroll
        for (int n = 0; n < 16; ++n) {
          h[n] = fmaf(__expf(sp * An[n]), h[n], dtx * bc[i][12 + n]);
          y = fmaf(h[n], bc[i][28 + n], y);
        }
        y = fmaf(xv, Dd, y);
        float sig = __builtin_amdgcn_rcpf(1.f + __expf(-zv));
        ytp[slot] = f2bf(y * (zv * sig));
      }
    }
  }
  // fused out_proj
  {
    int mt2 = w & 1;
    int ng = w >> 1;
    f32x4 acc[4];
#pragma unroll
    for (int j = 0; j < 4; ++j) acc[j] = (f32x4){0.f, 0.f, 0.f, 0.f};
    for (int kt = 0; kt < 6; ++kt) {
      __syncthreads();
#pragma unroll
      for (int ks = 0; ks < 2; ++ks) {
        int s = (ks << 2) + lk;
        bf16x8 a = *(const bf16x8*)&xsyt[kt * 2048 + (mt2 * 16 + lr) * 64 + ((s ^ (lr & 7)) << 3)];
#pragma unroll
        for (int j = 0; j < 4; ++j) {
          int br = (ng * 4 + j) * 16 + lr;
          bf16x8 bv = *(const bf16x8*)&BsW[br * 64 + ((s ^ (br & 7)) << 3)];
          acc[j] = MFMA16(a, bv, acc[j]);
        }
      }
      if (kt < 5) {
        __syncthreads();
        int k0 = (kt + 1) * 64;
#pragma unroll
        for (int j = 0; j < 4; ++j) {
          int row = j * 48 + (tid >> 3);
          int gc = k0 + (((tid & 7) ^ (row & 7)) << 3);
          gload16(Wo + (size_t)row * 384 + gc, &BsW[j * 3072 + (w << 9)]);
        }
      }
    }
#pragma unroll
    for (int j = 0; j < 4; ++j) {
      int c = (ng * 4 + j) * 16 + lr;
      size_t off = ((size_t)b * C_ + c) * L_ + l0 + mt2 * 16 + (lk << 2);
      f32x4 xv = *(const f32x4*)&x[off];
      *(f32x4*)&out[off] = acc[j] + xv;
    }
  }
}

extern "C" void kernel_launch(void* const* d_in, const int* in_sizes, int n_in,
                              void* d_out, int out_size, void* d_ws, size_t ws_size,
                              hipStream_t stream) {
  const float* x         = (const float*)d_in[0];
  const float* norm_w    = (const float*)d_in[1];
  const float* norm_b    = (const float*)d_in[2];
  const float* in_proj_w = (const float*)d_in[3];
  const float* conv_w    = (const float*)d_in[4];
  const float* conv_b    = (const float*)d_in[5];
  const float* x_proj_w  = (const float*)d_in[6];
  const float* dt_proj_w = (const float*)d_in[7];
  const float* dt_proj_b = (const float*)d_in[8];
  const float* A_log     = (const float*)d_in[9];
  const float* Dw        = (const float*)d_in[10];
  const float* out_proj_w= (const float*)d_in[11];
  float* out = (float*)d_out;
  float* ws = (float*)d_ws;

  unsigned short* seqn = (unsigned short*)(ws + F_SEQN);
  unsigned short* xin  = (unsigned short*)(ws + F_XIN);
  unsigned short* z    = (unsigned short*)(ws + F_Z);
  unsigned short* xsb  = (unsigned short*)(ws + F_XSB);
  float* dbl           = ws + F_DBL;
  unsigned short* dtb  = (unsigned short*)(ws + F_DT);
  float* Sbuf          = ws + F_SBUF;
  unsigned short* Hloc = (unsigned short*)(ws + F_HLOC);
  float* Spre          = ws + F_SPRE;
  float* Hsup          = ws + F_HSUP;
  float* Ssup          = ws + F_SSUP;
  unsigned short* wbuf = (unsigned short*)(ws + F_WBUF);
  unsigned short* ipw  = wbuf;
  unsigned short* xpw  = wbuf + 147456;
  unsigned short* opw  = wbuf + 165888;

  hipLaunchKernelGGL(k_ln, dim3(1960), dim3(256), 0, stream, x, norm_w, norm_b, seqn,
                     in_proj_w, x_proj_w, out_proj_w, wbuf);
  hipLaunchKernelGGL(k_inproj, dim3(128, 6), dim3(256), 0, stream, seqn, ipw, xin, z);

  int maxb = 0;
  hipError_t oe = hipOccupancyMaxActiveBlocksPerMultiprocessor(&maxb, k_mega, 384, 0);
  bool useMega = (oe == hipSuccess) && (maxb >= 2);

  if (useMega) {
    void* margs[] = {(void*)&xin, (void*)&conv_w, (void*)&conv_b, (void*)&xpw,
                     (void*)&dt_proj_w, (void*)&dt_proj_b, (void*)&A_log, (void*)&Dw,
                     (void*)&Hloc, (void*)&Sbuf, (void*)&Spre, (void*)&Hsup, (void*)&Ssup,
                     (void*)&z, (void*)&opw, (void*)&x, (void*)&out};
    hipLaunchCooperativeKernel((void*)k_mega, dim3(512), dim3(384), margs, 0, stream);
  } else {
    hipLaunchKernelGGL(k_convx, dim3(128, 4), dim3(384), 0, stream, xin, conv_w, conv_b, xpw,
                       dt_proj_w, dt_proj_b, A_log, xsb, dbl, dtb, Hloc, Sbuf);
    hipLaunchKernelGGL(k_scanB1, dim3(512), dim3(384), 0, stream, A_log, Hloc, Sbuf, Spre, Hsup,
                       Ssup);
    hipLaunchKernelGGL(k_scanC, dim3(512), dim3(384), 0, stream, xsb, dtb, dbl, z, A_log, Dw,
                       Hloc, Spre, Hsup, Ssup, opw, x, out);
  }
}

// Round 16
// 96.424 us; speedup vs baseline: 1.0775x; 1.0000x over previous
//
#include <hip/hip_runtime.h>
#include <hip/hip_bf16.h>
#include <hip/hip_cooperative_groups.h>

// Problem constants
constexpr int B_ = 4;
constexpr int C_ = 192;
constexpr int L_ = 4096;     // H*W
constexpr int DI = 384;      // d_inner
constexpr int DSs = 16;      // d_state
constexpr int DTR = 12;      // dt_rank
constexpr int NDBL = 44;     // dt_rank + 2*d_state
constexpr int NCHUNK = 128;  // scan chunks
constexpr int CSZ = 32;      // chunk size
constexpr int NSUP = 8;      // super-chunks (16 chunks each)

constexpr size_t BL = (size_t)B_ * L_;  // 16384

// Workspace offsets in FLOAT units (bf16 counted at half)
constexpr size_t F_SEQN = 0;                                   // bf16 BL*C
constexpr size_t F_XIN  = F_SEQN + BL * C_ / 2;                // bf16 BL*DI
constexpr size_t F_Z    = F_XIN + BL * DI / 2;                 // bf16 BL*DI
constexpr size_t F_XSB  = F_Z + BL * DI / 2;                   // bf16 BL*DI (fallback only)
constexpr size_t F_DBL  = F_XSB + BL * DI / 2;                 // f32  BL*NDBL (fallback only)
constexpr size_t F_DT   = F_DBL + BL * NDBL;                   // bf16 BL*DI (fallback only)
constexpr size_t F_SBUF = F_DT + BL * DI / 2;                  // f32  B*NCHUNK*DI
constexpr size_t F_HLOC = F_SBUF + (size_t)B_ * NCHUNK * DI;   // bf16 B*NCHUNK*16*DI
constexpr size_t F_SPRE = F_HLOC + (size_t)B_ * NCHUNK * DI * 16 / 2;  // f32 B*NCHUNK*DI
constexpr size_t F_HSUP = F_SPRE + (size_t)B_ * NCHUNK * DI;   // f32 B*NSUP*16*DI
constexpr size_t F_SSUP = F_HSUP + (size_t)B_ * NSUP * 16 * DI;// f32 B*NSUP*DI
constexpr size_t F_WBUF = F_SSUP + (size_t)B_ * NSUP * DI;     // bf16 weights
// total ~= 70 MB (prior rounds used 129 MB: safe)

typedef __attribute__((ext_vector_type(8))) short bf16x8;
typedef __attribute__((ext_vector_type(4))) float f32x4;

__device__ __forceinline__ unsigned short f2bf(float v) {
  unsigned x = __builtin_bit_cast(unsigned, v);
  unsigned r = x + 0x7FFFu + ((x >> 16) & 1u);   // RNE
  return (unsigned short)(r >> 16);
}
__device__ __forceinline__ float bf2f(unsigned short u) {
  return __builtin_bit_cast(float, (unsigned)u << 16);
}
__device__ __forceinline__ void gload16(const void* g, void* l) {
  __builtin_amdgcn_global_load_lds((const __attribute__((address_space(1))) void*)g,
                                   (__attribute__((address_space(3))) void*)l, 16, 0, 0);
}
#define MFMA16(a, b, c) __builtin_amdgcn_mfma_f32_16x16x32_bf16(a, b, c, 0, 0, 0)

// ---------------- LayerNorm (blocks 0..1023, 16-row tiles) + weight cvt tail ---------
__global__ __launch_bounds__(256) void k_ln(const float* __restrict__ x,
                                            const float* __restrict__ nw,
                                            const float* __restrict__ nb,
                                            unsigned short* __restrict__ seqn,
                                            const float* __restrict__ ipw,
                                            const float* __restrict__ xpw,
                                            const float* __restrict__ opw,
                                            unsigned short* __restrict__ wbuf) {
  if (blockIdx.x >= 1024) {
    int t = (blockIdx.x - 1024) * 256 + threadIdx.x;
    if (t < 239616) {
      float v;
      if (t < 147456) v = ipw[t];
      else if (t < 165888) {
        int j = t - 147456;
        int r = j / 384, c = j - r * 384;
        v = (r < 44) ? xpw[r * 384 + c] : 0.f;
      } else v = opw[t - 165888];
      wbuf[t] = f2bf(v);
    }
    return;
  }
  __shared__ unsigned short xt[192][18];
  __shared__ float ps[16][16], ps2[16][16];
  __shared__ float mu_[16], rs_[16];
  __shared__ float wsh[192], bsh[192];
  int tid = threadIdx.x;
  int blk = blockIdx.x;          // 0..1023
  int b = blk >> 8;
  int l0 = (blk & 255) << 4;
  const float* xb = x + (size_t)b * C_ * L_;
  for (int idx = tid; idx < 192 * 4; idx += 256) {
    int c = idx >> 2, lq = idx & 3;
    float4 v = *(const float4*)&xb[(size_t)c * L_ + l0 + (lq << 2)];
    ushort2 u0, u1;
    u0.x = f2bf(v.x); u0.y = f2bf(v.y);
    u1.x = f2bf(v.z); u1.y = f2bf(v.w);
    *(ushort2*)&xt[c][(lq << 2)] = u0;
    *(ushort2*)&xt[c][(lq << 2) + 2] = u1;
  }
  if (tid < 192) { wsh[tid] = nw[tid]; bsh[tid] = nb[tid]; }
  __syncthreads();
  int ll = tid & 15, q = tid >> 4;   // 16 groups x 12 channels
  float s = 0.f, ss = 0.f;
  for (int c = q * 12; c < q * 12 + 12; ++c) {
    float v = bf2f(xt[c][ll]);
    s += v; ss += v * v;
  }
  ps[q][ll] = s; ps2[q][ll] = ss;
  __syncthreads();
  if (q == 0) {
    float st = 0.f, sst = 0.f;
#pragma unroll
    for (int g = 0; g < 16; ++g) { st += ps[g][ll]; sst += ps2[g][ll]; }
    float mu = st * (1.f / 192.f);
    float var = sst * (1.f / 192.f) - mu * mu;
    mu_[ll] = mu; rs_[ll] = rsqrtf(var + 1e-5f);
  }
  __syncthreads();
  unsigned short* so = seqn + ((size_t)b * L_ + l0) * C_;
  for (int idx = tid; idx < 16 * 192; idx += 256) {
    int l = idx / 192, c = idx - l * 192;
    so[idx] = f2bf((bf2f(xt[c][l]) - mu_[l]) * rs_[l] * wsh[c] + bsh[c]);
  }
}

// ---------------- in_proj MFMA: seqn(BL,192)bf16 @ W(768,192)^T -> xin,z bf16 --------
__global__ __launch_bounds__(256) void k_inproj(const unsigned short* __restrict__ A,
                                                const unsigned short* __restrict__ W,
                                                unsigned short* __restrict__ xin,
                                                unsigned short* __restrict__ z) {
  __shared__ unsigned short smem[16384];
  unsigned short* As = smem;
  unsigned short* Bs = smem + 8192;
  int tid = threadIdx.x;
  int w = tid >> 6, l = tid & 63;
  int wr = w >> 1, wc = w & 1;
  int m0 = blockIdx.x << 7;
  int n0 = blockIdx.y << 7;
  f32x4 acc[4][4];
#pragma unroll
  for (int i = 0; i < 4; ++i)
#pragma unroll
    for (int j = 0; j < 4; ++j) acc[i][j] = (f32x4){0.f, 0.f, 0.f, 0.f};
  int lr = l & 15, lk = l >> 4;
  for (int kt = 0; kt < 3; ++kt) {
    int k0 = kt * 64;
    if (kt) __syncthreads();
#pragma unroll
    for (int i = 0; i < 4; ++i) {
      int row = (i << 5) + (tid >> 3);
      int gc = k0 + (((tid & 7) ^ (row & 7)) << 3);
      gload16(A + (size_t)(m0 + row) * 192 + gc, &As[(i << 11) + (w << 9)]);
      gload16(W + (size_t)(n0 + row) * 192 + gc, &Bs[(i << 11) + (w << 9)]);
    }
    __syncthreads();
#pragma unroll
    for (int ks = 0; ks < 2; ++ks) {
      int s = (ks << 2) + lk;
      bf16x8 af[4], bfr[4];
#pragma unroll
      for (int mi = 0; mi < 4; ++mi) {
        int r = (wr << 6) + (mi << 4) + lr;
        af[mi] = *(const bf16x8*)&As[r * 64 + ((s ^ (r & 7)) << 3)];
      }
#pragma unroll
      for (int ni = 0; ni < 4; ++ni) {
        int r = (wc << 6) + (ni << 4) + lr;
        bfr[ni] = *(const bf16x8*)&Bs[r * 64 + ((s ^ (r & 7)) << 3)];
      }
#pragma unroll
      for (int mi = 0; mi < 4; ++mi)
#pragma unroll
        for (int ni = 0; ni < 4; ++ni) acc[mi][ni] = MFMA16(af[mi], bfr[ni], acc[mi][ni]);
    }
  }
  __syncthreads();
#pragma unroll
  for (int mi = 0; mi < 4; ++mi)
#pragma unroll
    for (int ni = 0; ni < 4; ++ni) {
      int col = (wc << 6) + (ni << 4) + lr;
#pragma unroll
      for (int r = 0; r < 4; ++r) {
        int row = (wr << 6) + (mi << 4) + (lk << 2) + r;
        smem[(row << 7) + col] = f2bf(acc[mi][ni][r]);
      }
    }
  __syncthreads();
#pragma unroll
  for (int i = 0; i < 8; ++i) {
    int chunk = i * 256 + tid;
    int row = chunk >> 4, cq = chunk & 15;
    int n = n0 + (cq << 3);
    unsigned short* dst = (n < 384) ? (xin + (size_t)(m0 + row) * DI + n)
                                    : (z + (size_t)(m0 + row) * DI + (n - 384));
    *(bf16x8*)dst = *(const bf16x8*)&smem[(row << 7) + (cq << 3)];
  }
}

// ======================= FALLBACK PATH (round-13 + z prefetch) =======================
__global__ __launch_bounds__(384) void k_convx(const unsigned short* __restrict__ xin,
                                               const float* __restrict__ cw,
                                               const float* __restrict__ cb,
                                               const unsigned short* __restrict__ W,
                                               const float* __restrict__ dw,
                                               const float* __restrict__ dbias,
                                               const float* __restrict__ A_log,
                                               unsigned short* __restrict__ xsb,
                                               float* __restrict__ dbl,
                                               unsigned short* __restrict__ dtb,
                                               unsigned short* __restrict__ Hloc,
                                               float* __restrict__ Sbuf) {
  __shared__ unsigned short xs[6 * 2048];
  __shared__ unsigned short Bs[2][3072];
  __shared__ float dl[CSZ][12];
  __shared__ float Bsh2[CSZ][16];
  int tid = threadIdx.x;
  int w = tid >> 6, l = tid & 63;
  int b = blockIdx.y;
  int chunk = blockIdx.x;
  int l0 = chunk << 5;
  int d = tid;
  float4 w4 = *(const float4*)&cw[d * 4];
  float bb = cb[d];
  const unsigned short* xp = xin + ((size_t)b * L_ + l0) * DI + d;
  unsigned short* op = xsb + ((size_t)b * L_ + l0) * DI + d;
  float x0 = 0.f, x1 = 0.f, x2 = 0.f;
  if (l0 > 0) {
    x0 = bf2f(*(xp - 3 * DI));
    x1 = bf2f(*(xp - 2 * DI));
    x2 = bf2f(*(xp - DI));
  }
  int kt = d >> 6, col = d & 63, g = col >> 3, e = col & 7;
  unsigned short* xsrow = xs + kt * 2048;
  for (int r = 0; r < 32; ++r) {
    float xv = bf2f(xp[(size_t)r * DI]);
    float a = bb + w4.x * x0 + w4.y * x1 + w4.z * x2 + w4.w * xv;
    float sv = a * __builtin_amdgcn_rcpf(1.f + __expf(-a));
    unsigned short sb = f2bf(sv);
    xsrow[r * 64 + ((g ^ (r & 7)) << 3) + e] = sb;
    op[(size_t)r * DI] = sb;
    x0 = x1; x1 = x2; x2 = xv;
  }
  __syncthreads();
  int lr = l & 15, lk = l >> 4;
  int mt = w & 1, nt = w >> 1;
  {
    int row = tid >> 3;
    int gc = (((tid & 7) ^ (row & 7)) << 3);
    gload16(W + (size_t)row * 384 + gc, &Bs[0][w << 9]);
  }
  f32x4 accx = (f32x4){0.f, 0.f, 0.f, 0.f};
  for (int kt2 = 0; kt2 < 6; ++kt2) {
    __syncthreads();
    if (kt2 < 5) {
      int k0 = (kt2 + 1) * 64;
      int row = tid >> 3;
      int gc = k0 + (((tid & 7) ^ (row & 7)) << 3);
      gload16(W + (size_t)row * 384 + gc, &Bs[(kt2 + 1) & 1][w << 9]);
    }
    const unsigned short* Bcur = Bs[kt2 & 1];
#pragma unroll
    for (int ks = 0; ks < 2; ++ks) {
      int s = (ks << 2) + lk;
      int ar = (mt << 4) + lr;
      bf16x8 a = *(const bf16x8*)&xs[kt2 * 2048 + ar * 64 + ((s ^ (ar & 7)) << 3)];
      int br = (nt << 4) + lr;
      bf16x8 bbv = *(const bf16x8*)&Bcur[br * 64 + ((s ^ (br & 7)) << 3)];
      accx = MFMA16(a, bbv, accx);
    }
  }
  {
    int colq = (nt << 4) + lr;
#pragma unroll
    for (int r = 0; r < 4; ++r) {
      int row = (mt << 4) + (lk << 2) + r;
      float v = accx[r];
      if (colq < NDBL) dbl[((size_t)b * L_ + l0 + row) * NDBL + colq] = v;
      if (colq < 12) dl[row][colq] = v;
      else if (colq < 28) Bsh2[row][colq - 12] = v;
    }
  }
  __syncthreads();
  float4 wv0 = *(const float4*)&dw[d * 12];
  float4 wv1 = *(const float4*)&dw[d * 12 + 4];
  float4 wv2 = *(const float4*)&dw[d * 12 + 8];
  float bias = dbias[d];
  bool fast = true;
#pragma unroll
  for (int n = 0; n < 16; ++n) {
    float An_ = -__expf(A_log[d * 16 + n]);
    fast = fast && (fabsf(An_ + (float)(n + 1)) < 2e-3f);
  }
  unsigned short* dtp = dtb + ((size_t)b * L_ + l0) * DI + d;
  float h[16];
#pragma unroll
  for (int n = 0; n < 16; ++n) h[n] = 0.f;
  float S = 0.f;
  if (fast) {
#pragma unroll
    for (int i = 0; i < CSZ; ++i) {
      float4 c0 = *(const float4*)&dl[i][0];
      float4 c1 = *(const float4*)&dl[i][4];
      float4 c2 = *(const float4*)&dl[i][8];
      float a = bias;
      a = fmaf(wv0.x, c0.x, a); a = fmaf(wv0.y, c0.y, a);
      a = fmaf(wv0.z, c0.z, a); a = fmaf(wv0.w, c0.w, a);
      a = fmaf(wv1.x, c1.x, a); a = fmaf(wv1.y, c1.y, a);
      a = fmaf(wv1.z, c1.z, a); a = fmaf(wv1.w, c1.w, a);
      a = fmaf(wv2.x, c2.x, a); a = fmaf(wv2.y, c2.y, a);
      a = fmaf(wv2.z, c2.z, a); a = fmaf(wv2.w, c2.w, a);
      float sp = fmaxf(a, 0.f) + __logf(1.f + __expf(-fabsf(a)));
      dtp[(size_t)i * DI] = f2bf(sp);
      S += sp;
      float xv = bf2f(xsrow[i * 64 + ((g ^ (i & 7)) << 3) + e]);
      float dtx = sp * xv;
      float r = __expf(-sp);
      float r2 = r * r;
      float r4 = r2 * r2;
      float dA0 = r, dA1 = r2, dA2 = r2 * r, dA3 = r4;
#pragma unroll
      for (int gg = 0; gg < 4; ++gg) {
        float4 Bg = *(const float4*)&Bsh2[i][gg << 2];
        h[(gg << 2) + 0] = fmaf(dA0, h[(gg << 2) + 0], dtx * Bg.x);
        h[(gg << 2) + 1] = fmaf(dA1, h[(gg << 2) + 1], dtx * Bg.y);
        h[(gg << 2) + 2] = fmaf(dA2, h[(gg << 2) + 2], dtx * Bg.z);
        h[(gg << 2) + 3] = fmaf(dA3, h[(gg << 2) + 3], dtx * Bg.w);
        if (gg < 3) { dA0 *= r4; dA1 *= r4; dA2 *= r4; dA3 *= r4; }
      }
    }
  } else {
    float An[16];
#pragma unroll
    for (int n = 0; n < 16; ++n) An[n] = -__expf(A_log[d * 16 + n]);
#pragma unroll
    for (int i = 0; i < CSZ; ++i) {
      float4 c0 = *(const float4*)&dl[i][0];
      float4 c1 = *(const float4*)&dl[i][4];
      float4 c2 = *(const float4*)&dl[i][8];
      float a = bias;
      a = fmaf(wv0.x, c0.x, a); a = fmaf(wv0.y, c0.y, a);
      a = fmaf(wv0.z, c0.z, a); a = fmaf(wv0.w, c0.w, a);
      a = fmaf(wv1.x, c1.x, a); a = fmaf(wv1.y, c1.y, a);
      a = fmaf(wv1.z, c1.z, a); a = fmaf(wv1.w, c1.w, a);
      a = fmaf(wv2.x, c2.x, a); a = fmaf(wv2.y, c2.y, a);
      a = fmaf(wv2.z, c2.z, a); a = fmaf(wv2.w, c2.w, a);
      float sp = fmaxf(a, 0.f) + __logf(1.f + __expf(-fabsf(a)));
      dtp[(size_t)i * DI] = f2bf(sp);
      S += sp;
      float xv = bf2f(xsrow[i * 64 + ((g ^ (i & 7)) << 3) + e]);
      float dtx = sp * xv;
#pragma unroll
      for (int n = 0; n < 16; ++n)
        h[n] = fmaf(__expf(sp * An[n]), h[n], dtx * Bsh2[i][n]);
    }
  }
  size_t hbase = ((size_t)(b * NCHUNK + chunk) * 16) * DI + d;
#pragma unroll
  for (int n = 0; n < 16; ++n) Hloc[hbase + (size_t)n * DI] = f2bf(h[n]);
  Sbuf[((size_t)b * NCHUNK + chunk) * DI + d] = S;
}

__global__ __launch_bounds__(384) void k_scanB1(const float* __restrict__ A_log,
                                                unsigned short* __restrict__ Hloc,
                                                const float* __restrict__ Sbuf,
                                                float* __restrict__ Spre,
                                                float* __restrict__ Hsup,
                                                float* __restrict__ Ssup) {
  int d = threadIdx.x;
  int blk = blockIdx.x;
  int n = blk & 15;
  int s = (blk >> 4) & 7;
  int b = blk >> 7;
  float An = -__expf(A_log[d * 16 + n]);
  float h = 0.f, Sp = 0.f;
  int c0 = s * 16;
#pragma unroll
  for (int i = 0; i < 16; ++i) {
    int c = c0 + i;
    size_t hidx = (((size_t)(b * NCHUNK + c) * 16) + n) * DI + d;
    float Hl = bf2f(Hloc[hidx]);
    float S = Sbuf[((size_t)b * NCHUNK + c) * DI + d];
    Hloc[hidx] = f2bf(h);
    if (n == 0) Spre[((size_t)b * NCHUNK + c) * DI + d] = Sp;
    h = fmaf(__expf(An * S), h, Hl);
    Sp += S;
  }
  Hsup[(((size_t)(b * NSUP + s) * 16) + n) * DI + d] = h;
  if (n == 0) Ssup[((size_t)b * NSUP + s) * DI + d] = Sp;
}

__global__ __launch_bounds__(384) void k_scanC(const unsigned short* __restrict__ xsb,
                                               const unsigned short* __restrict__ dtb,
                                               const float* __restrict__ dbl,
                                               const unsigned short* __restrict__ z,
                                               const float* __restrict__ A_log,
                                               const float* __restrict__ Dw,
                                               const unsigned short* __restrict__ Hloc,
                                               const float* __restrict__ Spre,
                                               const float* __restrict__ Hsup,
                                               const float* __restrict__ Ssup,
                                               const unsigned short* __restrict__ Wo,
                                               const float* __restrict__ x,
                                               float* __restrict__ out) {
  __shared__ float BCsh[CSZ][32];
  __shared__ unsigned short yt[6 * 2048];
  __shared__ unsigned short Bs[12288];
  int tid = threadIdx.x;
  int blk = blockIdx.x;
  int b = blk >> 7;
  int chunk = blk & (NCHUNK - 1);
  int l0 = chunk << 5;
  int d = tid;
  int w = tid >> 6, l = tid & 63;
  // early z prefetch into packed regs: HBM/cross-XCD latency hides under W/BCsh/carry
  const unsigned short* zp = z + ((size_t)b * L_ + l0) * DI + d;
  unsigned zpk[16];
#pragma unroll
  for (int i = 0; i < 16; ++i) {
    unsigned short a0 = zp[(size_t)(2 * i) * DI];
    unsigned short a1 = zp[(size_t)(2 * i + 1) * DI];
    zpk[i] = (unsigned)a0 | (((unsigned)a1) << 16);
  }
#pragma unroll
  for (int j = 0; j < 4; ++j) {
    int row = j * 48 + (tid >> 3);
    int gc = (((tid & 7) ^ (row & 7)) << 3);
    gload16(Wo + (size_t)row * 384 + gc, &Bs[j * 3072 + (w << 9)]);
  }
  for (int idx = tid; idx < CSZ * 32; idx += 384) {
    int r = idx >> 5, n32 = idx & 31;
    BCsh[r][n32] = dbl[((size_t)b * L_ + l0 + r) * NDBL + DTR + n32];
  }
  float Dd = Dw[d];
  bool fast = true;
#pragma unroll
  for (int n = 0; n < 16; ++n) {
    float An_ = -__expf(A_log[d * 16 + n]);
    fast = fast && (fabsf(An_ + (float)(n + 1)) < 2e-3f);
  }
  int sup = chunk >> 4;
  size_t hbase = ((size_t)(b * NCHUNK + chunk) * 16) * DI + d;
  float Spv = Spre[((size_t)b * NCHUNK + chunk) * DI + d];
  float h[16];
  if (fast) {
    float I[16];
#pragma unroll
    for (int n = 0; n < 16; ++n) I[n] = 0.f;
    for (int s = 0; s < sup; ++s) {
      float Ss = Ssup[((size_t)b * NSUP + s) * DI + d];
      const float* Hs = Hsup + ((size_t)(b * NSUP + s) * 16) * DI + d;
      float t = __expf(-Ss);
      float t2 = t * t, t4 = t2 * t2;
      float p0 = t, p1 = t2, p2 = t2 * t, p3 = t4;
#pragma unroll
      for (int gI = 0; gI < 4; ++gI) {
        I[(gI << 2) + 0] = fmaf(p0, I[(gI << 2) + 0], Hs[(size_t)((gI << 2) + 0) * DI]);
        I[(gI << 2) + 1] = fmaf(p1, I[(gI << 2) + 1], Hs[(size_t)((gI << 2) + 1) * DI]);
        I[(gI << 2) + 2] = fmaf(p2, I[(gI << 2) + 2], Hs[(size_t)((gI << 2) + 2) * DI]);
        I[(gI << 2) + 3] = fmaf(p3, I[(gI << 2) + 3], Hs[(size_t)((gI << 2) + 3) * DI]);
        if (gI < 3) { p0 *= t4; p1 *= t4; p2 *= t4; p3 *= t4; }
      }
    }
    float t = __expf(-Spv);
    float t2 = t * t, t4 = t2 * t2;
    float p0 = t, p1 = t2, p2 = t2 * t, p3 = t4;
#pragma unroll
    for (int gI = 0; gI < 4; ++gI) {
      h[(gI << 2) + 0] = fmaf(p0, I[(gI << 2) + 0], bf2f(Hloc[hbase + (size_t)((gI << 2) + 0) * DI]));
      h[(gI << 2) + 1] = fmaf(p1, I[(gI << 2) + 1], bf2f(Hloc[hbase + (size_t)((gI << 2) + 1) * DI]));
      h[(gI << 2) + 2] = fmaf(p2, I[(gI << 2) + 2], bf2f(Hloc[hbase + (size_t)((gI << 2) + 2) * DI]));
      h[(gI << 2) + 3] = fmaf(p3, I[(gI << 2) + 3], bf2f(Hloc[hbase + (size_t)((gI << 2) + 3) * DI]));
      if (gI < 3) { p0 *= t4; p1 *= t4; p2 *= t4; p3 *= t4; }
    }
  } else {
    float An[16];
#pragma unroll
    for (int n = 0; n < 16; ++n) An[n] = -__expf(A_log[d * 16 + n]);
    float I[16];
#pragma unroll
    for (int n = 0; n < 16; ++n) I[n] = 0.f;
    for (int s = 0; s < sup; ++s) {
      float Ss = Ssup[((size_t)b * NSUP + s) * DI + d];
      const float* Hs = Hsup + ((size_t)(b * NSUP + s) * 16) * DI + d;
#pragma unroll
      for (int n = 0; n < 16; ++n)
        I[n] = fmaf(__expf(An[n] * Ss), I[n], Hs[(size_t)n * DI]);
    }
#pragma unroll
    for (int n = 0; n < 16; ++n)
      h[n] = fmaf(__expf(An[n] * Spv), I[n], bf2f(Hloc[hbase + (size_t)n * DI]));
  }
  const unsigned short* xp = xsb + ((size_t)b * L_ + l0) * DI + d;
  const unsigned short* dtp = dtb + ((size_t)b * L_ + l0) * DI + d;
  int ktile = d >> 6, colq = d & 63, gq = colq >> 3, eq = colq & 7;
  unsigned short* ytp = yt + ktile * 2048;
  __syncthreads();
  if (fast) {
#pragma unroll
    for (int i = 0; i < CSZ; ++i) {
      float sp = bf2f(dtp[(size_t)i * DI]);
      float xv = bf2f(xp[(size_t)i * DI]);
      unsigned short zu = (i & 1) ? (unsigned short)(zpk[i >> 1] >> 16)
                                  : (unsigned short)(zpk[i >> 1] & 0xFFFFu);
      float zv = bf2f(zu);
      float dtx = sp * xv;
      float r = __expf(-sp);
      float r2 = r * r;
      float r4 = r2 * r2;
      float dA0 = r, dA1 = r2, dA2 = r2 * r, dA3 = r4;
      float y = 0.f;
#pragma unroll
      for (int g = 0; g < 4; ++g) {
        float4 Bg = *(const float4*)&BCsh[i][g << 2];
        float4 Cg = *(const float4*)&BCsh[i][16 + (g << 2)];
        h[(g << 2) + 0] = fmaf(dA0, h[(g << 2) + 0], dtx * Bg.x);
        h[(g << 2) + 1] = fmaf(dA1, h[(g << 2) + 1], dtx * Bg.y);
        h[(g << 2) + 2] = fmaf(dA2, h[(g << 2) + 2], dtx * Bg.z);
        h[(g << 2) + 3] = fmaf(dA3, h[(g << 2) + 3], dtx * Bg.w);
        y = fmaf(h[(g << 2) + 0], Cg.x, y);
        y = fmaf(h[(g << 2) + 1], Cg.y, y);
        y = fmaf(h[(g << 2) + 2], Cg.z, y);
        y = fmaf(h[(g << 2) + 3], Cg.w, y);
        if (g < 3) { dA0 *= r4; dA1 *= r4; dA2 *= r4; dA3 *= r4; }
      }
      y = fmaf(xv, Dd, y);
      float sig = __builtin_amdgcn_rcpf(1.f + __expf(-zv));
      ytp[i * 64 + ((gq ^ (i & 7)) << 3) + eq] = f2bf(y * (zv * sig));
    }
  } else {
    float An[16];
#pragma unroll
    for (int n = 0; n < 16; ++n) An[n] = -__expf(A_log[d * 16 + n]);
#pragma unroll
    for (int i = 0; i < CSZ; ++i) {
      float sp = bf2f(dtp[(size_t)i * DI]);
      float xv = bf2f(xp[(size_t)i * DI]);
      unsigned short zu = (i & 1) ? (unsigned short)(zpk[i >> 1] >> 16)
                                  : (unsigned short)(zpk[i >> 1] & 0xFFFFu);
      float zv = bf2f(zu);
      float dtx = sp * xv;
      float y = 0.f;
#pragma unroll
      for (int n = 0; n < 16; ++n) {
        h[n] = fmaf(__expf(sp * An[n]), h[n], dtx * BCsh[i][n]);
        y = fmaf(h[n], BCsh[i][16 + n], y);
      }
      y = fmaf(xv, Dd, y);
      float sig = __builtin_amdgcn_rcpf(1.f + __expf(-zv));
      ytp[i * 64 + ((gq ^ (i & 7)) << 3) + eq] = f2bf(y * (zv * sig));
    }
  }
  int lr = l & 15, lk = l >> 4;
  int mt = w & 1;
  int ng = w >> 1;
  f32x4 acc[4];
#pragma unroll
  for (int j = 0; j < 4; ++j) acc[j] = (f32x4){0.f, 0.f, 0.f, 0.f};
  for (int kt = 0; kt < 6; ++kt) {
    __syncthreads();
#pragma unroll
    for (int ks = 0; ks < 2; ++ks) {
      int s = (ks << 2) + lk;
      bf16x8 a = *(const bf16x8*)&yt[kt * 2048 + (mt * 16 + lr) * 64 + ((s ^ (lr & 7)) << 3)];
#pragma unroll
      for (int j = 0; j < 4; ++j) {
        int br = (ng * 4 + j) * 16 + lr;
        bf16x8 bv = *(const bf16x8*)&Bs[br * 64 + ((s ^ (br & 7)) << 3)];
        acc[j] = MFMA16(a, bv, acc[j]);
      }
    }
    if (kt < 5) {
      __syncthreads();
      int k0 = (kt + 1) * 64;
#pragma unroll
      for (int j = 0; j < 4; ++j) {
        int row = j * 48 + (tid >> 3);
        int gc = k0 + (((tid & 7) ^ (row & 7)) << 3);
        gload16(Wo + (size_t)row * 384 + gc, &Bs[j * 3072 + (w << 9)]);
      }
    }
  }
#pragma unroll
  for (int j = 0; j < 4; ++j) {
    int c = (ng * 4 + j) * 16 + lr;
    size_t off = ((size_t)b * C_ + c) * L_ + l0 + mt * 16 + (lk << 2);
    f32x4 xv = *(const f32x4*)&x[off];
    *(f32x4*)&out[off] = acc[j] + xv;
  }
}

// ================= COOPERATIVE MEGA (Wo double-buffered in phase C) ==================
__global__ __launch_bounds__(384) void k_mega(const unsigned short* __restrict__ xin,
                                              const float* __restrict__ cw,
                                              const float* __restrict__ cb,
                                              const unsigned short* __restrict__ W,
                                              const float* __restrict__ dw,
                                              const float* __restrict__ dbias,
                                              const float* __restrict__ A_log,
                                              const float* __restrict__ Dw,
                                              unsigned short* __restrict__ Hloc,
                                              float* __restrict__ Sbuf,
                                              float* __restrict__ Spre,
                                              float* __restrict__ Hsup,
                                              float* __restrict__ Ssup,
                                              const unsigned short* __restrict__ z,
                                              const unsigned short* __restrict__ Wo,
                                              const float* __restrict__ x,
                                              float* __restrict__ out) {
  __shared__ unsigned short xsyt[6 * 2048];   // conv-out tiles; phase C: overwritten by y
  __shared__ unsigned short BsW[12288];       // A: x_proj W dbuf (2x3072); C: Wo buf0
  __shared__ unsigned short BsW2[12288];      // C: Wo buf1
  __shared__ float bc[CSZ][44];               // dbl (persists A -> C)
  namespace cg = cooperative_groups;
  cg::grid_group grid = cg::this_grid();
  int tid = threadIdx.x;
  int bid = blockIdx.x;       // 512
  int b = bid >> 7;
  int chunk = bid & 127;
  int l0 = chunk << 5;
  int d = tid;
  int w = tid >> 6, l = tid & 63;
  int lr = l & 15, lk = l >> 4;
  int ktA = d >> 6, colA = d & 63, g = colA >> 3, e = colA & 7;
  unsigned dtpk[16];   // packed bf16 dt pairs, persist across grid syncs

  // phase A1: conv + SiLU -> LDS only
  {
    float4 w4 = *(const float4*)&cw[d * 4];
    float bb = cb[d];
    const unsigned short* xp = xin + ((size_t)b * L_ + l0) * DI + d;
    float x0 = 0.f, x1 = 0.f, x2 = 0.f;
    if (l0 > 0) {
      x0 = bf2f(*(xp - 3 * DI));
      x1 = bf2f(*(xp - 2 * DI));
      x2 = bf2f(*(xp - DI));
    }
    unsigned short* xsrow = xsyt + ktA * 2048;
#pragma unroll
    for (int r = 0; r < 32; ++r) {
      float xv = bf2f(xp[(size_t)r * DI]);
      float a = bb + w4.x * x0 + w4.y * x1 + w4.z * x2 + w4.w * xv;
      float sv = a * __builtin_amdgcn_rcpf(1.f + __expf(-a));
      xsrow[r * 64 + ((g ^ (r & 7)) << 3) + e] = f2bf(sv);
      x0 = x1; x1 = x2; x2 = xv;
    }
  }
  __syncthreads();
  // phase A2: x_proj MFMA (6-wave, dbuf W)
  int mt = w & 1, nt = w >> 1;
  {
    int row = tid >> 3;
    int gc = (((tid & 7) ^ (row & 7)) << 3);
    gload16(W + (size_t)row * 384 + gc, &BsW[w << 9]);
  }
  f32x4 accx = (f32x4){0.f, 0.f, 0.f, 0.f};
  for (int kt2 = 0; kt2 < 6; ++kt2) {
    __syncthreads();
    if (kt2 < 5) {
      int k0 = (kt2 + 1) * 64;
      int row = tid >> 3;
      int gc = k0 + (((tid & 7) ^ (row & 7)) << 3);
      gload16(W + (size_t)row * 384 + gc, &BsW[((kt2 + 1) & 1) * 3072 + (w << 9)]);
    }
    const unsigned short* Bcur = BsW + (kt2 & 1) * 3072;
#pragma unroll
    for (int ks = 0; ks < 2; ++ks) {
      int s = (ks << 2) + lk;
      int ar = (mt << 4) + lr;
      bf16x8 a = *(const bf16x8*)&xsyt[kt2 * 2048 + ar * 64 + ((s ^ (ar & 7)) << 3)];
      int br = (nt << 4) + lr;
      bf16x8 bbv = *(const bf16x8*)&Bcur[br * 64 + ((s ^ (br & 7)) << 3)];
      accx = MFMA16(a, bbv, accx);
    }
  }
  // phase A3: dbl -> LDS bc
  {
    int colq = (nt << 4) + lr;
#pragma unroll
    for (int r = 0; r < 4; ++r) {
      int row = (mt << 4) + (lk << 2) + r;
      if (colq < NDBL) bc[row][colq] = accx[r];
    }
  }
  __syncthreads();
  // phase A4: dt_proj + chunk-local scan (x from LDS)
  bool fast = true;
#pragma unroll
  for (int n = 0; n < 16; ++n) {
    float An_ = -__expf(A_log[d * 16 + n]);
    fast = fast && (fabsf(An_ + (float)(n + 1)) < 2e-3f);
  }
  float h[16];
#pragma unroll
  for (int n = 0; n < 16; ++n) h[n] = 0.f;
  {
    float4 wv0 = *(const float4*)&dw[d * 12];
    float4 wv1 = *(const float4*)&dw[d * 12 + 4];
    float4 wv2 = *(const float4*)&dw[d * 12 + 8];
    float bias = dbias[d];
    const unsigned short* xsrow = xsyt + ktA * 2048;
    float S = 0.f;
    if (fast) {
#pragma unroll
      for (int i = 0; i < CSZ; ++i) {
        float4 c0 = *(const float4*)&bc[i][0];
        float4 c1 = *(const float4*)&bc[i][4];
        float4 c2 = *(const float4*)&bc[i][8];
        float a = bias;
        a = fmaf(wv0.x, c0.x, a); a = fmaf(wv0.y, c0.y, a);
        a = fmaf(wv0.z, c0.z, a); a = fmaf(wv0.w, c0.w, a);
        a = fmaf(wv1.x, c1.x, a); a = fmaf(wv1.y, c1.y, a);
        a = fmaf(wv1.z, c1.z, a); a = fmaf(wv1.w, c1.w, a);
        a = fmaf(wv2.x, c2.x, a); a = fmaf(wv2.y, c2.y, a);
        a = fmaf(wv2.z, c2.z, a); a = fmaf(wv2.w, c2.w, a);
        float sp = fmaxf(a, 0.f) + __logf(1.f + __expf(-fabsf(a)));
        unsigned short su = f2bf(sp);
        if ((i & 1) == 0) dtpk[i >> 1] = (unsigned)su;
        else dtpk[i >> 1] |= ((unsigned)su) << 16;
        S += sp;
        float xv = bf2f(xsrow[i * 64 + ((g ^ (i & 7)) << 3) + e]);
        float dtx = sp * xv;
        float r = __expf(-sp);
        float r2 = r * r;
        float r4 = r2 * r2;
        float dA0 = r, dA1 = r2, dA2 = r2 * r, dA3 = r4;
#pragma unroll
        for (int gg = 0; gg < 4; ++gg) {
          float4 Bg = *(const float4*)&bc[i][12 + (gg << 2)];
          h[(gg << 2) + 0] = fmaf(dA0, h[(gg << 2) + 0], dtx * Bg.x);
          h[(gg << 2) + 1] = fmaf(dA1, h[(gg << 2) + 1], dtx * Bg.y);
          h[(gg << 2) + 2] = fmaf(dA2, h[(gg << 2) + 2], dtx * Bg.z);
          h[(gg << 2) + 3] = fmaf(dA3, h[(gg << 2) + 3], dtx * Bg.w);
          if (gg < 3) { dA0 *= r4; dA1 *= r4; dA2 *= r4; dA3 *= r4; }
        }
      }
    } else {
      float An[16];
#pragma unroll
      for (int n = 0; n < 16; ++n) An[n] = -__expf(A_log[d * 16 + n]);
#pragma unroll
      for (int i = 0; i < CSZ; ++i) {
        float4 c0 = *(const float4*)&bc[i][0];
        float4 c1 = *(const float4*)&bc[i][4];
        float4 c2 = *(const float4*)&bc[i][8];
        float a = bias;
        a = fmaf(wv0.x, c0.x, a); a = fmaf(wv0.y, c0.y, a);
        a = fmaf(wv0.z, c0.z, a); a = fmaf(wv0.w, c0.w, a);
        a = fmaf(wv1.x, c1.x, a); a = fmaf(wv1.y, c1.y, a);
        a = fmaf(wv1.z, c1.z, a); a = fmaf(wv1.w, c1.w, a);
        a = fmaf(wv2.x, c2.x, a); a = fmaf(wv2.y, c2.y, a);
        a = fmaf(wv2.z, c2.z, a); a = fmaf(wv2.w, c2.w, a);
        float sp = fmaxf(a, 0.f) + __logf(1.f + __expf(-fabsf(a)));
        unsigned short su = f2bf(sp);
        if ((i & 1) == 0) dtpk[i >> 1] = (unsigned)su;
        else dtpk[i >> 1] |= ((unsigned)su) << 16;
        S += sp;
        float xv = bf2f(xsrow[i * 64 + ((g ^ (i & 7)) << 3) + e]);
        float dtx = sp * xv;
#pragma unroll
        for (int n = 0; n < 16; ++n)
          h[n] = fmaf(__expf(sp * An[n]), h[n], dtx * bc[i][12 + n]);
      }
    }
    size_t hbase = ((size_t)(b * NCHUNK + chunk) * 16) * DI + d;
#pragma unroll
    for (int n = 0; n < 16; ++n) Hloc[hbase + (size_t)n * DI] = f2bf(h[n]);
    Sbuf[((size_t)b * NCHUNK + chunk) * DI + d] = S;
  }
  grid.sync();
  // phase B1: per-super local prefix + super totals
  {
    int n2 = bid & 15;
    int s2 = (bid >> 4) & 7;
    int b2 = bid >> 7;
    float An = -__expf(A_log[d * 16 + n2]);
    float hh = 0.f, Sp = 0.f;
    int c0 = s2 * 16;
#pragma unroll
    for (int i = 0; i < 16; ++i) {
      int c = c0 + i;
      size_t hidx = (((size_t)(b2 * NCHUNK + c) * 16) + n2) * DI + d;
      float Hl = bf2f(Hloc[hidx]);
      float Sv = Sbuf[((size_t)b2 * NCHUNK + c) * DI + d];
      Hloc[hidx] = f2bf(hh);
      if (n2 == 0) Spre[((size_t)b2 * NCHUNK + c) * DI + d] = Sp;
      hh = fmaf(__expf(An * Sv), hh, Hl);
      Sp += Sv;
    }
    Hsup[(((size_t)(b2 * NSUP + s2) * 16) + n2) * DI + d] = hh;
    if (n2 == 0) Ssup[((size_t)b2 * NSUP + s2) * DI + d] = Sp;
  }
  grid.sync();
  // phase C: Wo prefetch (buf0) + inline super-carry + scan replay + out_proj
#pragma unroll
  for (int j = 0; j < 4; ++j) {
    int row = j * 48 + (tid >> 3);
    int gc = (((tid & 7) ^ (row & 7)) << 3);
    gload16(Wo + (size_t)row * 384 + gc, &BsW[j * 3072 + (w << 9)]);
  }
  float Dd = Dw[d];
  int sup = chunk >> 4;
  size_t hbase = ((size_t)(b * NCHUNK + chunk) * 16) * DI + d;
  float Spv = Spre[((size_t)b * NCHUNK + chunk) * DI + d];
  if (fast) {
    float I[16];
#pragma unroll
    for (int n = 0; n < 16; ++n) I[n] = 0.f;
    for (int s = 0; s < sup; ++s) {
      float Ss = Ssup[((size_t)b * NSUP + s) * DI + d];
      const float* Hs = Hsup + ((size_t)(b * NSUP + s) * 16) * DI + d;
      float t = __expf(-Ss);
      float t2 = t * t, t4 = t2 * t2;
      float p0 = t, p1 = t2, p2 = t2 * t, p3 = t4;
#pragma unroll
      for (int gI = 0; gI < 4; ++gI) {
        I[(gI << 2) + 0] = fmaf(p0, I[(gI << 2) + 0], Hs[(size_t)((gI << 2) + 0) * DI]);
        I[(gI << 2) + 1] = fmaf(p1, I[(gI << 2) + 1], Hs[(size_t)((gI << 2) + 1) * DI]);
        I[(gI << 2) + 2] = fmaf(p2, I[(gI << 2) + 2], Hs[(size_t)((gI << 2) + 2) * DI]);
        I[(gI << 2) + 3] = fmaf(p3, I[(gI << 2) + 3], Hs[(size_t)((gI << 2) + 3) * DI]);
        if (gI < 3) { p0 *= t4; p1 *= t4; p2 *= t4; p3 *= t4; }
      }
    }
    float t = __expf(-Spv);
    float t2 = t * t, t4 = t2 * t2;
    float p0 = t, p1 = t2, p2 = t2 * t, p3 = t4;
#pragma unroll
    for (int gI = 0; gI < 4; ++gI) {
      h[(gI << 2) + 0] = fmaf(p0, I[(gI << 2) + 0], bf2f(Hloc[hbase + (size_t)((gI << 2) + 0) * DI]));
      h[(gI << 2) + 1] = fmaf(p1, I[(gI << 2) + 1], bf2f(Hloc[hbase + (size_t)((gI << 2) + 1) * DI]));
      h[(gI << 2) + 2] = fmaf(p2, I[(gI << 2) + 2], bf2f(Hloc[hbase + (size_t)((gI << 2) + 2) * DI]));
      h[(gI << 2) + 3] = fmaf(p3, I[(gI << 2) + 3], bf2f(Hloc[hbase + (size_t)((gI << 2) + 3) * DI]));
      if (gI < 3) { p0 *= t4; p1 *= t4; p2 *= t4; p3 *= t4; }
    }
  } else {
    float An[16];
#pragma unroll
    for (int n = 0; n < 16; ++n) An[n] = -__expf(A_log[d * 16 + n]);
    float I[16];
#pragma unroll
    for (int n = 0; n < 16; ++n) I[n] = 0.f;
    for (int s = 0; s < sup; ++s) {
      float Ss = Ssup[((size_t)b * NSUP + s) * DI + d];
      const float* Hs = Hsup + ((size_t)(b * NSUP + s) * 16) * DI + d;
#pragma unroll
      for (int n = 0; n < 16; ++n)
        I[n] = fmaf(__expf(An[n] * Ss), I[n], Hs[(size_t)n * DI]);
    }
#pragma unroll
    for (int n = 0; n < 16; ++n)
      h[n] = fmaf(__expf(An[n] * Spv), I[n], bf2f(Hloc[hbase + (size_t)n * DI]));
  }
  // scan replay: x read from LDS slot, then overwritten with y (same-thread slot)
  {
    const unsigned short* zp = z + ((size_t)b * L_ + l0) * DI + d;
    unsigned short* ytp = xsyt + ktA * 2048;
    if (fast) {
#pragma unroll
      for (int i = 0; i < CSZ; ++i) {
        unsigned short du = (i & 1) ? (unsigned short)(dtpk[i >> 1] >> 16)
                                    : (unsigned short)(dtpk[i >> 1] & 0xFFFFu);
        int slot = i * 64 + ((g ^ (i & 7)) << 3) + e;
        float sp = bf2f(du);
        float xv = bf2f(ytp[slot]);
        float zv = bf2f(zp[(size_t)i * DI]);
        float dtx = sp * xv;
        float r = __expf(-sp);
        float r2 = r * r;
        float r4 = r2 * r2;
        float dA0 = r, dA1 = r2, dA2 = r2 * r, dA3 = r4;
        float y = 0.f;
#pragma unroll
        for (int gg = 0; gg < 4; ++gg) {
          float4 Bg = *(const float4*)&bc[i][12 + (gg << 2)];
          float4 Cg = *(const float4*)&bc[i][28 + (gg << 2)];
          h[(gg << 2) + 0] = fmaf(dA0, h[(gg << 2) + 0], dtx * Bg.x);
          h[(gg << 2) + 1] = fmaf(dA1, h[(gg << 2) + 1], dtx * Bg.y);
          h[(gg << 2) + 2] = fmaf(dA2, h[(gg << 2) + 2], dtx * Bg.z);
          h[(gg << 2) + 3] = fmaf(dA3, h[(gg << 2) + 3], dtx * Bg.w);
          y = fmaf(h[(gg << 2) + 0], Cg.x, y);
          y = fmaf(h[(gg << 2) + 1], Cg.y, y);
          y = fmaf(h[(gg << 2) + 2], Cg.z, y);
          y = fmaf(h[(gg << 2) + 3], Cg.w, y);
          if (gg < 3) { dA0 *= r4; dA1 *= r4; dA2 *= r4; dA3 *= r4; }
        }
        y = fmaf(xv, Dd, y);
        float sig = __builtin_amdgcn_rcpf(1.f + __expf(-zv));
        ytp[slot] = f2bf(y * (zv * sig));
      }
    } else {
      float An[16];
#pragma unroll
      for (int n = 0; n < 16; ++n) An[n] = -__expf(A_log[d * 16 + n]);
#pragma unroll
      for (int i = 0; i < CSZ; ++i) {
        unsigned short du = (i & 1) ? (unsigned short)(dtpk[i >> 1] >> 16)
                                    : (unsigned short)(dtpk[i >> 1] & 0xFFFFu);
        int slot = i * 64 + ((g ^ (i & 7)) << 3) + e;
        float sp = bf2f(du);
        float xv = bf2f(ytp[slot]);
        float zv = bf2f(zp[(size_t)i * DI]);
        float dtx = sp * xv;
        float y = 0.f;
#pragma unroll
        for (int n = 0; n < 16; ++n) {
          h[n] = fmaf(__expf(sp * An[n]), h[n], dtx * bc[i][12 + n]);
          y = fmaf(h[n], bc[i][28 + n], y);
        }
        y = fmaf(xv, Dd, y);
        float sig = __builtin_amdgcn_rcpf(1.f + __expf(-zv));
        ytp[slot] = f2bf(y * (zv * sig));
      }
    }
  }
  // fused out_proj with Wo double-buffer: one barrier per K-step
  {
    int mt2 = w & 1;
    int ng = w >> 1;
    f32x4 acc[4];
#pragma unroll
    for (int j = 0; j < 4; ++j) acc[j] = (f32x4){0.f, 0.f, 0.f, 0.f};
    for (int kt = 0; kt < 6; ++kt) {
      __syncthreads();  // yt ready (kt=0); this kt's staged Wo buffer ready
      if (kt < 5) {
        int k0 = (kt + 1) * 64;
        unsigned short* dstb = ((kt + 1) & 1) ? BsW2 : BsW;
#pragma unroll
        for (int j = 0; j < 4; ++j) {
          int row = j * 48 + (tid >> 3);
          int gc = k0 + (((tid & 7) ^ (row & 7)) << 3);
          gload16(Wo + (size_t)row * 384 + gc, &dstb[j * 3072 + (w << 9)]);
        }
      }
      const unsigned short* Bcur = (kt & 1) ? BsW2 : BsW;
#pragma unroll
      for (int ks = 0; ks < 2; ++ks) {
        int s = (ks << 2) + lk;
        bf16x8 a = *(const bf16x8*)&xsyt[kt * 2048 + (mt2 * 16 + lr) * 64 + ((s ^ (lr & 7)) << 3)];
#pragma unroll
        for (int j = 0; j < 4; ++j) {
          int br = (ng * 4 + j) * 16 + lr;
          bf16x8 bv = *(const bf16x8*)&Bcur[br * 64 + ((s ^ (br & 7)) << 3)];
          acc[j] = MFMA16(a, bv, acc[j]);
        }
      }
    }
#pragma unroll
    for (int j = 0; j < 4; ++j) {
      int c = (ng * 4 + j) * 16 + lr;
      size_t off = ((size_t)b * C_ + c) * L_ + l0 + mt2 * 16 + (lk << 2);
      f32x4 xv = *(const f32x4*)&x[off];
      *(f32x4*)&out[off] = acc[j] + xv;
    }
  }
}

extern "C" void kernel_launch(void* const* d_in, const int* in_sizes, int n_in,
                              void* d_out, int out_size, void* d_ws, size_t ws_size,
                              hipStream_t stream) {
  const float* x         = (const float*)d_in[0];
  const float* norm_w    = (const float*)d_in[1];
  const float* norm_b    = (const float*)d_in[2];
  const float* in_proj_w = (const float*)d_in[3];
  const float* conv_w    = (const float*)d_in[4];
  const float* conv_b    = (const float*)d_in[5];
  const float* x_proj_w  = (const float*)d_in[6];
  const float* dt_proj_w = (const float*)d_in[7];
  const float* dt_proj_b = (const float*)d_in[8];
  const float* A_log     = (const float*)d_in[9];
  const float* Dw        = (const float*)d_in[10];
  const float* out_proj_w= (const float*)d_in[11];
  float* out = (float*)d_out;
  float* ws = (float*)d_ws;

  unsigned short* seqn = (unsigned short*)(ws + F_SEQN);
  unsigned short* xin  = (unsigned short*)(ws + F_XIN);
  unsigned short* z    = (unsigned short*)(ws + F_Z);
  unsigned short* xsb  = (unsigned short*)(ws + F_XSB);
  float* dbl           = ws + F_DBL;
  unsigned short* dtb  = (unsigned short*)(ws + F_DT);
  float* Sbuf          = ws + F_SBUF;
  unsigned short* Hloc = (unsigned short*)(ws + F_HLOC);
  float* Spre          = ws + F_SPRE;
  float* Hsup          = ws + F_HSUP;
  float* Ssup          = ws + F_SSUP;
  unsigned short* wbuf = (unsigned short*)(ws + F_WBUF);
  unsigned short* ipw  = wbuf;
  unsigned short* xpw  = wbuf + 147456;
  unsigned short* opw  = wbuf + 165888;

  hipLaunchKernelGGL(k_ln, dim3(1960), dim3(256), 0, stream, x, norm_w, norm_b, seqn,
                     in_proj_w, x_proj_w, out_proj_w, wbuf);
  hipLaunchKernelGGL(k_inproj, dim3(128, 6), dim3(256), 0, stream, seqn, ipw, xin, z);

  int maxb = 0;
  hipError_t oe = hipOccupancyMaxActiveBlocksPerMultiprocessor(&maxb, k_mega, 384, 0);
  bool useMega = (oe == hipSuccess) && (maxb >= 2);

  if (useMega) {
    void* margs[] = {(void*)&xin, (void*)&conv_w, (void*)&conv_b, (void*)&xpw,
                     (void*)&dt_proj_w, (void*)&dt_proj_b, (void*)&A_log, (void*)&Dw,
                     (void*)&Hloc, (void*)&Sbuf, (void*)&Spre, (void*)&Hsup, (void*)&Ssup,
                     (void*)&z, (void*)&opw, (void*)&x, (void*)&out};
    hipLaunchCooperativeKernel((void*)k_mega, dim3(512), dim3(384), margs, 0, stream);
  } else {
    hipLaunchKernelGGL(k_convx, dim3(128, 4), dim3(384), 0, stream, xin, conv_w, conv_b, xpw,
                       dt_proj_w, dt_proj_b, A_log, xsb, dbl, dtb, Hloc, Sbuf);
    hipLaunchKernelGGL(k_scanB1, dim3(512), dim3(384), 0, stream, A_log, Hloc, Sbuf, Spre, Hsup,
                       Ssup);
    hipLaunchKernelGGL(k_scanC, dim3(512), dim3(384), 0, stream, xsb, dtb, dbl, z, A_log, Dw,
                       Hloc, Spre, Hsup, Ssup, opw, x, out);
  }
}